// Round 1
// baseline (952.700 us; speedup 1.0000x reference)
//
#include <hip/hip_runtime.h>

typedef __attribute__((ext_vector_type(8))) short short8;
typedef __attribute__((ext_vector_type(4))) float f32x4;

#define DEV static __device__ __forceinline__

DEV float bf2f(unsigned short u) {
  union { unsigned int u32; float f; } v; v.u32 = ((unsigned int)u) << 16; return v.f;
}
DEV unsigned short f2bf(float f) {
  union { float f; unsigned int u; } v; v.f = f;
  unsigned int r = v.u + 0x7fffu + ((v.u >> 16) & 1u);
  return (unsigned short)(r >> 16);
}

constexpr int D  = 512;
constexpr int BT = 32768;   // B*T rows

// ---------------- K1: fp32 -> bf16 conversion (x, Wq|Wk|Wv concat, Wo) ----------------
__global__ __launch_bounds__(256) void k_convert(
    const float* __restrict__ x, const float* __restrict__ Wq, const float* __restrict__ Wk,
    const float* __restrict__ Wv, const float* __restrict__ Wo,
    unsigned short* __restrict__ xb, unsigned short* __restrict__ wqkv,
    unsigned short* __restrict__ wo_b) {
  int idx = blockIdx.x * 256 + threadIdx.x;
  const int NX4 = (BT * D) / 4;      // 4,194,304
  const float* src; unsigned short* dst; size_t i4;
  if (idx < NX4) {
    src = x; dst = xb; i4 = (size_t)idx * 4;
  } else {
    int t = idx - NX4;
    int w = t >> 16;                 // NW4 = 512*512/4 = 65536
    int within = t & 65535;
    src = (w == 0) ? Wq : (w == 1) ? Wk : (w == 2) ? Wv : Wo;
    dst = (w < 3) ? (wqkv + (size_t)w * D * D) : wo_b;
    i4 = (size_t)within * 4;
  }
  float4 v = *(const float4*)(src + i4);
  ushort4 o; o.x = f2bf(v.x); o.y = f2bf(v.y); o.z = f2bf(v.z); o.w = f2bf(v.w);
  *(ushort4*)(dst + i4) = o;
}

// ---------------- K2: QKV GEMM (NT). Q,K row-major bf16; V stored transposed per chunk ----------------
// grid = 1024 (512 m-blocks x 2 n-halves), block = 256 (4 waves, 16 rows each)
__global__ __launch_bounds__(256) void k_qkv(
    const unsigned short* __restrict__ xb, const unsigned short* __restrict__ wqkv,
    unsigned short* __restrict__ q, unsigned short* __restrict__ kbuf,
    unsigned short* __restrict__ vt) {
  int lane = threadIdx.x & 63, w = threadIdx.x >> 6;
  int lr = lane & 15, lg = lane >> 4;
  int mb = blockIdx.x >> 1, nh = blockIdx.x & 1;
  int row0 = mb * 64 + w * 16;
  const unsigned short* arow = xb + (size_t)(row0 + lr) * D + lg * 8;
  for (int ns = 0; ns < 12; ++ns) {
    int n0 = nh * 768 + ns * 64;
    f32x4 acc[4];
    #pragma unroll
    for (int j = 0; j < 4; ++j) acc[j] = (f32x4){0.f, 0.f, 0.f, 0.f};
    #pragma unroll 4
    for (int kk = 0; kk < 16; ++kk) {
      short8 a = *(const short8*)(arow + kk * 32);
      #pragma unroll
      for (int j = 0; j < 4; ++j) {
        short8 b = *(const short8*)(wqkv + (size_t)(n0 + j * 16 + lr) * D + kk * 32 + lg * 8);
        acc[j] = __builtin_amdgcn_mfma_f32_16x16x32_bf16(a, b, acc[j], 0, 0, 0);
      }
    }
    #pragma unroll
    for (int j = 0; j < 4; ++j) {
      int col = n0 + j * 16 + lr;
      #pragma unroll
      for (int r = 0; r < 4; ++r) {
        int row = row0 + lg * 4 + r;
        unsigned short val = f2bf(acc[j][r]);
        if (col < 512)       q[(size_t)row * D + col] = val;
        else if (col < 1024) kbuf[(size_t)row * D + (col - 512)] = val;
        else {
          int e = col - 1024, bc = row >> 9, key = row & 511;
          vt[(size_t)(bc * 512 + e) * 512 + key] = val;   // Vt[bc][feature][key]
        }
      }
    }
  }
}

// ---------------- K3: local attention, one block per (chunk, head, 64-q-rows) ----------------
// grid = 4096 = 64 chunks x 8 heads x 8 q-blocks; block = 256 (4 waves x 16 q-rows)
__global__ __launch_bounds__(256, 2) void k_attn(
    const unsigned short* __restrict__ Q, const unsigned short* __restrict__ K,
    const unsigned short* __restrict__ Vt, unsigned short* __restrict__ attn_out) {
  __shared__ unsigned short plds[4 * 16 * 512];   // 64 KB, 16 KB per wave
  int lane = threadIdx.x & 63, w = threadIdx.x >> 6;
  int lr = lane & 15, lg = lane >> 4;
  int qb = blockIdx.x & 7, h = (blockIdx.x >> 3) & 7, bc = blockIdx.x >> 6;
  int qrow0 = bc * 512 + qb * 64 + w * 16;
  const unsigned short* qp = Q + (size_t)(qrow0 + lr) * D + h * 64 + lg * 8;
  short8 aq0 = *(const short8*)(qp);
  short8 aq1 = *(const short8*)(qp + 32);

  f32x4 acc[32];
  #pragma unroll
  for (int nt = 0; nt < 32; ++nt) acc[nt] = (f32x4){0.f, 0.f, 0.f, 0.f};
  #pragma unroll
  for (int nt = 0; nt < 32; ++nt) {
    const unsigned short* kp = K + (size_t)(bc * 512 + nt * 16 + lr) * D + h * 64 + lg * 8;
    short8 b0 = *(const short8*)(kp);
    short8 b1 = *(const short8*)(kp + 32);
    acc[nt] = __builtin_amdgcn_mfma_f32_16x16x32_bf16(aq0, b0, acc[nt], 0, 0, 0);
    acc[nt] = __builtin_amdgcn_mfma_f32_16x16x32_bf16(aq1, b1, acc[nt], 0, 0, 0);
  }

  // row softmax (rows = lg*4 + r), fp32, wave-parallel: reduce over 32 reg-slots then 16 lanes
  float rmax[4] = {-1e30f, -1e30f, -1e30f, -1e30f};
  #pragma unroll
  for (int nt = 0; nt < 32; ++nt) {
    #pragma unroll
    for (int r = 0; r < 4; ++r) rmax[r] = fmaxf(rmax[r], acc[nt][r]);
  }
  #pragma unroll
  for (int r = 0; r < 4; ++r) {
    #pragma unroll
    for (int m = 1; m < 16; m <<= 1) rmax[r] = fmaxf(rmax[r], __shfl_xor(rmax[r], m));
  }
  const float scale = 0.125f;   // 1/sqrt(64)
  float rsum[4] = {0.f, 0.f, 0.f, 0.f};
  #pragma unroll
  for (int nt = 0; nt < 32; ++nt) {
    #pragma unroll
    for (int r = 0; r < 4; ++r) {
      float p = __expf((acc[nt][r] - rmax[r]) * scale);
      acc[nt][r] = p; rsum[r] += p;
    }
  }
  #pragma unroll
  for (int r = 0; r < 4; ++r) {
    #pragma unroll
    for (int m = 1; m < 16; m <<= 1) rsum[r] += __shfl_xor(rsum[r], m);
  }

  // write unnormalized P (bf16) to LDS, XOR-swizzled (row stride 1KB -> 16-way conflict otherwise)
  char* pbase = (char*)plds + w * 16384;
  #pragma unroll
  for (int nt = 0; nt < 32; ++nt) {
    #pragma unroll
    for (int r = 0; r < 4; ++r) {
      int prow = lg * 4 + r, pcol = nt * 16 + lr;
      int byt = (prow * 1024 + pcol * 2) ^ ((prow & 7) << 4);
      *(unsigned short*)(pbase + byt) = f2bf(acc[nt][r]);
    }
  }
  __syncthreads();

  // PV: A = P from LDS (swizzled read), B^T = Vt rows (contiguous)
  f32x4 oacc[4];
  #pragma unroll
  for (int j = 0; j < 4; ++j) oacc[j] = (f32x4){0.f, 0.f, 0.f, 0.f};
  #pragma unroll 4
  for (int kk = 0; kk < 16; ++kk) {
    int byt = (lr * 1024 + kk * 64 + lg * 16) ^ ((lr & 7) << 4);
    short8 a = *(const short8*)(pbase + byt);
    #pragma unroll
    for (int j = 0; j < 4; ++j) {
      const unsigned short* vp = Vt + (size_t)(bc * 512 + h * 64 + j * 16 + lr) * 512 + kk * 32 + lg * 8;
      short8 b = *(const short8*)vp;
      oacc[j] = __builtin_amdgcn_mfma_f32_16x16x32_bf16(a, b, oacc[j], 0, 0, 0);
    }
  }
  float inv[4];
  #pragma unroll
  for (int r = 0; r < 4; ++r) inv[r] = 1.f / rsum[r];
  #pragma unroll
  for (int j = 0; j < 4; ++j) {
    int col = h * 64 + j * 16 + lr;
    #pragma unroll
    for (int r = 0; r < 4; ++r) {
      int row = qrow0 + lg * 4 + r;
      attn_out[(size_t)row * D + col] = f2bf(oacc[j][r] * inv[r]);
    }
  }
}

// ---------------- K4: Wo GEMM (NT), output bf16 ----------------
__global__ __launch_bounds__(256) void k_wo(
    const unsigned short* __restrict__ ain, const unsigned short* __restrict__ wo_b,
    unsigned short* __restrict__ lout) {
  int lane = threadIdx.x & 63, w = threadIdx.x >> 6;
  int lr = lane & 15, lg = lane >> 4;
  int mb = blockIdx.x >> 1, nh = blockIdx.x & 1;
  int row0 = mb * 64 + w * 16;
  const unsigned short* arow = ain + (size_t)(row0 + lr) * D + lg * 8;
  for (int ns = 0; ns < 4; ++ns) {
    int n0 = nh * 256 + ns * 64;
    f32x4 acc[4];
    #pragma unroll
    for (int j = 0; j < 4; ++j) acc[j] = (f32x4){0.f, 0.f, 0.f, 0.f};
    #pragma unroll 4
    for (int kk = 0; kk < 16; ++kk) {
      short8 a = *(const short8*)(arow + kk * 32);
      #pragma unroll
      for (int j = 0; j < 4; ++j) {
        short8 b = *(const short8*)(wo_b + (size_t)(n0 + j * 16 + lr) * D + kk * 32 + lg * 8);
        acc[j] = __builtin_amdgcn_mfma_f32_16x16x32_bf16(a, b, acc[j], 0, 0, 0);
      }
    }
    #pragma unroll
    for (int j = 0; j < 4; ++j) {
      int col = n0 + j * 16 + lr;
      #pragma unroll
      for (int r = 0; r < 4; ++r)
        lout[(size_t)(row0 + lg * 4 + r) * D + col] = f2bf(acc[j][r]);
    }
  }
}

// ---------------- K4b: per-chunk mean -> summaries fp32 [64][512] ----------------
__global__ __launch_bounds__(256) void k_mean(const unsigned short* __restrict__ lout,
                                              float* __restrict__ summ) {
  int bc = blockIdx.x;
  int col = blockIdx.y * 256 + threadIdx.x;
  const unsigned short* p = lout + (size_t)bc * 512 * 512 + col;
  float s = 0.f;
  #pragma unroll 8
  for (int r = 0; r < 512; ++r) s += bf2f(p[(size_t)r * 512]);
  summ[bc * 512 + col] = s * (1.f / 512.f);
}

// ---------------- K5a: sg = summaries @ Wg.T (fp32, tiny) ----------------
__global__ __launch_bounds__(256) void k_sg(const float* __restrict__ summ,
                                            const float* __restrict__ Wg,
                                            float* __restrict__ sg) {
  __shared__ float srow[512];
  int m = blockIdx.x >> 1, half = blockIdx.x & 1;
  for (int i = threadIdx.x; i < 512; i += 256) srow[i] = summ[m * 512 + i];
  __syncthreads();
  int n = half * 256 + threadIdx.x;
  const float* wr = Wg + (size_t)n * 512;
  float s = 0.f;
  #pragma unroll 8
  for (int kk = 0; kk < 512; ++kk) s += srow[kk] * wr[kk];
  sg[m * 512 + n] = s;
}

// ---------------- K5b: cross-chunk attention (fp32, tiny): one block per (batch, head) ----------------
__global__ __launch_bounds__(256) void k_gattn(const float* __restrict__ sg,
                                               float* __restrict__ gctx) {
  __shared__ float qs[32][64];
  __shared__ float sc[32][32];
  int b = blockIdx.x >> 3, h = blockIdx.x & 7;
  int tid = threadIdx.x;
  for (int i = tid; i < 2048; i += 256) {
    int r = i >> 6, e = i & 63;
    qs[r][e] = sg[(size_t)(b * 32 + r) * 512 + h * 64 + e];
  }
  __syncthreads();
  for (int p = tid; p < 1024; p += 256) {
    int qi = p >> 5, ki = p & 31;
    float s = 0.f;
    #pragma unroll 8
    for (int e = 0; e < 64; ++e) s += qs[qi][e] * qs[ki][e];
    sc[qi][ki] = s * 0.125f;
  }
  __syncthreads();
  if (tid < 32) {
    float mx = -1e30f;
    for (int k2 = 0; k2 < 32; ++k2) mx = fmaxf(mx, sc[tid][k2]);
    float sm = 0.f;
    for (int k2 = 0; k2 < 32; ++k2) { float p = __expf(sc[tid][k2] - mx); sc[tid][k2] = p; sm += p; }
    float iv = 1.f / sm;
    for (int k2 = 0; k2 < 32; ++k2) sc[tid][k2] *= iv;
  }
  __syncthreads();
  for (int i = tid; i < 2048; i += 256) {
    int r = i >> 6, e = i & 63;
    float o = 0.f;
    #pragma unroll 8
    for (int k2 = 0; k2 < 32; ++k2) o += sc[r][k2] * qs[k2][e];
    gctx[(size_t)(b * 32 + r) * 512 + h * 64 + e] = o;
  }
}

// ---------------- K6: out = local_out + broadcast(gctx), fp32 output ----------------
__global__ __launch_bounds__(256) void k_final(const unsigned short* __restrict__ lout,
                                               const float* __restrict__ gctx,
                                               float* __restrict__ out) {
  size_t idx = (size_t)blockIdx.x * 256 + threadIdx.x;
  size_t i = idx * 4;
  int c = (int)(i & 511);
  int bcg = (int)(i >> 18);   // (i>>9) = row; row>>9 = global chunk
  ushort4 lv = *(const ushort4*)(lout + i);
  float4 g = *(const float4*)(gctx + (size_t)bcg * 512 + c);
  float4 o;
  o.x = bf2f(lv.x) + g.x;
  o.y = bf2f(lv.y) + g.y;
  o.z = bf2f(lv.z) + g.z;
  o.w = bf2f(lv.w) + g.w;
  *(float4*)(out + i) = o;
}

extern "C" void kernel_launch(void* const* d_in, const int* in_sizes, int n_in,
                              void* d_out, int out_size, void* d_ws, size_t ws_size,
                              hipStream_t stream) {
  const float* x  = (const float*)d_in[0];
  const float* Wq = (const float*)d_in[1];
  const float* Wk = (const float*)d_in[2];
  const float* Wv = (const float*)d_in[3];
  const float* Wo = (const float*)d_in[4];
  const float* Wg = (const float*)d_in[5];
  float* out = (float*)d_out;

  // workspace layout (total 136,708,096 B ≈ 130.4 MiB)
  char* ws = (char*)d_ws;
  unsigned short* xb   = (unsigned short*)(ws);                 // 32 MB  [A]
  unsigned short* q    = (unsigned short*)(ws + 33554432);      // 32 MB  [B]
  unsigned short* kb   = (unsigned short*)(ws + 67108864);      // 32 MB  [C]
  unsigned short* vt   = (unsigned short*)(ws + 100663296);     // 32 MB  [D]
  unsigned short* wqkv = (unsigned short*)(ws + 134217728);     // 1.5 MB
  unsigned short* wo_b = (unsigned short*)(ws + 135790592);     // 0.5 MB
  float* summ = (float*)(ws + 136314880);                       // 128 KB
  float* sgp  = (float*)(ws + 136445952);                       // 128 KB
  float* gctx = (float*)(ws + 136577024);                       // 128 KB
  unsigned short* attn_out = xb;   // region A reused (xb dead after k_qkv)
  unsigned short* local_bf = q;    // region B reused (q dead after k_attn)

  k_convert<<<17408, 256, 0, stream>>>(x, Wq, Wk, Wv, Wo, xb, wqkv, wo_b);
  k_qkv<<<1024, 256, 0, stream>>>(xb, wqkv, q, kb, vt);
  k_attn<<<4096, 256, 0, stream>>>(q, kb, vt, attn_out);
  k_wo<<<1024, 256, 0, stream>>>(attn_out, wo_b, local_bf);
  k_mean<<<dim3(64, 2), 256, 0, stream>>>(local_bf, summ);
  k_sg<<<128, 256, 0, stream>>>(summ, Wg, sgp);
  k_gattn<<<16, 256, 0, stream>>>(sgp, gctx);
  k_final<<<16384, 256, 0, stream>>>(local_bf, gctx, out);
}

// Round 2
// 492.836 us; speedup vs baseline: 1.9331x; 1.9331x over previous
//
#include <hip/hip_runtime.h>

typedef __attribute__((ext_vector_type(8))) short short8;
typedef __attribute__((ext_vector_type(4))) float f32x4;

#define DEV static __device__ __forceinline__

DEV float bf2f(unsigned short u) {
  union { unsigned int u32; float f; } v; v.u32 = ((unsigned int)u) << 16; return v.f;
}
DEV unsigned short f2bf(float f) {
  union { float f; unsigned int u; } v; v.f = f;
  unsigned int r = v.u + 0x7fffu + ((v.u >> 16) & 1u);
  return (unsigned short)(r >> 16);
}

// async global->LDS, 16B per lane; LDS dest is wave-uniform base + lane*16
#define GLL16(g, l) __builtin_amdgcn_global_load_lds( \
    (const __attribute__((address_space(1))) void*)(g), \
    (__attribute__((address_space(3))) void*)(l), 16, 0, 0)

constexpr int D  = 512;
constexpr int BT = 32768;   // B*T rows

// ---------------- K1: fp32 -> bf16 conversion (x, Wq|Wk|Wv concat, Wo) ----------------
__global__ __launch_bounds__(256) void k_convert(
    const float* __restrict__ x, const float* __restrict__ Wq, const float* __restrict__ Wk,
    const float* __restrict__ Wv, const float* __restrict__ Wo,
    unsigned short* __restrict__ xb, unsigned short* __restrict__ wqkv,
    unsigned short* __restrict__ wo_b) {
  int idx = blockIdx.x * 256 + threadIdx.x;
  const int NX4 = (BT * D) / 4;      // 4,194,304
  const float* src; unsigned short* dst; size_t i4;
  if (idx < NX4) {
    src = x; dst = xb; i4 = (size_t)idx * 4;
  } else {
    int t = idx - NX4;
    int w = t >> 16;                 // NW4 = 512*512/4 = 65536
    int within = t & 65535;
    src = (w == 0) ? Wq : (w == 1) ? Wk : (w == 2) ? Wv : Wo;
    dst = (w < 3) ? (wqkv + (size_t)w * D * D) : wo_b;
    i4 = (size_t)within * 4;
  }
  float4 v = *(const float4*)(src + i4);
  ushort4 o; o.x = f2bf(v.x); o.y = f2bf(v.y); o.z = f2bf(v.z); o.w = f2bf(v.w);
  *(ushort4*)(dst + i4) = o;
}

// ---------------- m97-structure GEMM: C[M,N] = A[M,512] x B[N,512]^T ----------------
// 128x128 tile, BK=32, 4 waves (2x2), global_load_lds staging, 2 barriers/K-step.
// EPI 0: C -> O0 row-major bf16 [M][512].
// EPI 1: QKV scatter: cols 0-511 -> O0 (q), 512-1023 -> O1 (k), 1024-1535 -> O2 = Vt[bc][e][key].
template<int NBLK, int EPI>
__global__ __launch_bounds__(256) void k_gemm(
    const unsigned short* __restrict__ A, const unsigned short* __restrict__ Bm,
    unsigned short* __restrict__ O0, unsigned short* __restrict__ O1,
    unsigned short* __restrict__ O2) {
  __shared__ unsigned short Ash[128 * 32];   // [row][k], 64 B rows, linear for global_load_lds
  __shared__ unsigned short Bsh[128 * 32];
  const int tid = threadIdx.x;
  const int lane = tid & 63, w = tid >> 6;
  const int lr = lane & 15, lg = lane >> 4;
  // bijective XCD-chunked swizzle (gridDim %8 == 0 for all instantiations)
  const int cpx = gridDim.x >> 3;
  const int bid = blockIdx.x;
  const int work = (bid & 7) * cpx + (bid >> 3);
  const int nb = work % NBLK, mb = work / NBLK;
  const int m0 = mb * 128, n0 = nb * 128;
  const int wr = w >> 1, wc = w & 1;

  // staging: wave w fills LDS chunks [w*1024, w*1024+512) elems = rows w*32..w*32+31
  const int srow = w * 32 + (lane >> 2);
  const int scol = (lane & 3) * 8;
  const unsigned short* gA = A + (size_t)(m0 + srow) * D + scol;
  const unsigned short* gB = Bm + (size_t)(n0 + srow) * D + scol;

  f32x4 acc[4][4];
  #pragma unroll
  for (int m = 0; m < 4; ++m)
    #pragma unroll
    for (int n = 0; n < 4; ++n) acc[m][n] = (f32x4){0.f, 0.f, 0.f, 0.f};

  for (int kt = 0; kt < 16; ++kt) {
    __syncthreads();                      // prior reads done before overwrite
    const unsigned short* a0 = gA + kt * 32;
    const unsigned short* b0 = gB + kt * 32;
    GLL16(a0,            &Ash[w * 1024]);
    GLL16(a0 + 16 * D,   &Ash[w * 1024 + 512]);
    GLL16(b0,            &Bsh[w * 1024]);
    GLL16(b0 + 16 * D,   &Bsh[w * 1024 + 512]);
    __syncthreads();                      // vmcnt(0) drain + barrier
    short8 af[4], bf[4];
    #pragma unroll
    for (int m = 0; m < 4; ++m)
      af[m] = *(const short8*)&Ash[(wr * 64 + m * 16 + lr) * 32 + lg * 8];
    #pragma unroll
    for (int n = 0; n < 4; ++n)
      bf[n] = *(const short8*)&Bsh[(wc * 64 + n * 16 + lr) * 32 + lg * 8];
    #pragma unroll
    for (int m = 0; m < 4; ++m)
      #pragma unroll
      for (int n = 0; n < 4; ++n)
        acc[m][n] = __builtin_amdgcn_mfma_f32_16x16x32_bf16(af[m], bf[n], acc[m][n], 0, 0, 0);
  }

  #pragma unroll
  for (int m = 0; m < 4; ++m) {
    #pragma unroll
    for (int n = 0; n < 4; ++n) {
      int col = n0 + wc * 64 + n * 16 + lr;
      #pragma unroll
      for (int r = 0; r < 4; ++r) {
        int row = m0 + wr * 64 + m * 16 + lg * 4 + r;
        unsigned short val = f2bf(acc[m][n][r]);
        if (EPI == 0) {
          O0[(size_t)row * D + col] = val;
        } else {
          if (col < 512)       O0[(size_t)row * D + col] = val;
          else if (col < 1024) O1[(size_t)row * D + (col - 512)] = val;
          else {
            int e = col - 1024, bc = row >> 9, key = row & 511;
            O2[(size_t)(bc * 512 + e) * 512 + key] = val;   // Vt[bc][feature][key]
          }
        }
      }
    }
  }
}

// ---------------- K3: local attention, one block per (chunk, head, 64-q-rows) ----------------
// grid = 4096 = 64 chunks x 8 heads x 8 q-blocks; block = 256 (4 waves x 16 q-rows)
__global__ __launch_bounds__(256, 2) void k_attn(
    const unsigned short* __restrict__ Q, const unsigned short* __restrict__ K,
    const unsigned short* __restrict__ Vt, unsigned short* __restrict__ attn_out) {
  __shared__ unsigned short plds[4 * 16 * 512];   // 64 KB, 16 KB per wave
  int lane = threadIdx.x & 63, w = threadIdx.x >> 6;
  int lr = lane & 15, lg = lane >> 4;
  // XCD swizzle: 512 consecutive works (all qb,h for 8 chunks) per XCD -> K/V slices L2-resident
  int work = ((blockIdx.x & 7) << 9) + (blockIdx.x >> 3);
  int qb = work & 7, h = (work >> 3) & 7, bc = work >> 6;
  int qrow0 = bc * 512 + qb * 64 + w * 16;
  const unsigned short* qp = Q + (size_t)(qrow0 + lr) * D + h * 64 + lg * 8;
  short8 aq0 = *(const short8*)(qp);
  short8 aq1 = *(const short8*)(qp + 32);

  f32x4 acc[32];
  #pragma unroll
  for (int nt = 0; nt < 32; ++nt) acc[nt] = (f32x4){0.f, 0.f, 0.f, 0.f};
  #pragma unroll
  for (int nt = 0; nt < 32; ++nt) {
    const unsigned short* kp = K + (size_t)(bc * 512 + nt * 16 + lr) * D + h * 64 + lg * 8;
    short8 b0 = *(const short8*)(kp);
    short8 b1 = *(const short8*)(kp + 32);
    acc[nt] = __builtin_amdgcn_mfma_f32_16x16x32_bf16(aq0, b0, acc[nt], 0, 0, 0);
    acc[nt] = __builtin_amdgcn_mfma_f32_16x16x32_bf16(aq1, b1, acc[nt], 0, 0, 0);
  }

  // row softmax (rows = lg*4 + r), fp32, wave-parallel: reduce over 32 reg-slots then 16 lanes
  float rmax[4] = {-1e30f, -1e30f, -1e30f, -1e30f};
  #pragma unroll
  for (int nt = 0; nt < 32; ++nt) {
    #pragma unroll
    for (int r = 0; r < 4; ++r) rmax[r] = fmaxf(rmax[r], acc[nt][r]);
  }
  #pragma unroll
  for (int r = 0; r < 4; ++r) {
    #pragma unroll
    for (int m = 1; m < 16; m <<= 1) rmax[r] = fmaxf(rmax[r], __shfl_xor(rmax[r], m));
  }
  const float scale = 0.125f;   // 1/sqrt(64)
  float rsum[4] = {0.f, 0.f, 0.f, 0.f};
  #pragma unroll
  for (int nt = 0; nt < 32; ++nt) {
    #pragma unroll
    for (int r = 0; r < 4; ++r) {
      float p = __expf((acc[nt][r] - rmax[r]) * scale);
      acc[nt][r] = p; rsum[r] += p;
    }
  }
  #pragma unroll
  for (int r = 0; r < 4; ++r) {
    #pragma unroll
    for (int m = 1; m < 16; m <<= 1) rsum[r] += __shfl_xor(rsum[r], m);
  }

  // write unnormalized P (bf16) to LDS, XOR-swizzled (row stride 1KB -> 16-way conflict otherwise)
  char* pbase = (char*)plds + w * 16384;
  #pragma unroll
  for (int nt = 0; nt < 32; ++nt) {
    #pragma unroll
    for (int r = 0; r < 4; ++r) {
      int prow = lg * 4 + r, pcol = nt * 16 + lr;
      int byt = (prow * 1024 + pcol * 2) ^ ((prow & 7) << 4);
      *(unsigned short*)(pbase + byt) = f2bf(acc[nt][r]);
    }
  }
  __syncthreads();

  // PV: A = P from LDS (swizzled read), B^T = Vt rows (contiguous)
  f32x4 oacc[4];
  #pragma unroll
  for (int j = 0; j < 4; ++j) oacc[j] = (f32x4){0.f, 0.f, 0.f, 0.f};
  #pragma unroll 4
  for (int kk = 0; kk < 16; ++kk) {
    int byt = (lr * 1024 + kk * 64 + lg * 16) ^ ((lr & 7) << 4);
    short8 a = *(const short8*)(pbase + byt);
    #pragma unroll
    for (int j = 0; j < 4; ++j) {
      const unsigned short* vp = Vt + (size_t)(bc * 512 + h * 64 + j * 16 + lr) * 512 + kk * 32 + lg * 8;
      short8 b = *(const short8*)vp;
      oacc[j] = __builtin_amdgcn_mfma_f32_16x16x32_bf16(a, b, oacc[j], 0, 0, 0);
    }
  }
  float inv[4];
  #pragma unroll
  for (int r = 0; r < 4; ++r) inv[r] = 1.f / rsum[r];
  #pragma unroll
  for (int j = 0; j < 4; ++j) {
    int col = h * 64 + j * 16 + lr;
    #pragma unroll
    for (int r = 0; r < 4; ++r) {
      int row = qrow0 + lg * 4 + r;
      attn_out[(size_t)row * D + col] = f2bf(oacc[j][r] * inv[r]);
    }
  }
}

// ---------------- K4b: per-chunk mean -> summaries fp32 [64][512] ----------------
__global__ __launch_bounds__(256) void k_mean(const unsigned short* __restrict__ lout,
                                              float* __restrict__ summ) {
  int bc = blockIdx.x;
  int col = blockIdx.y * 256 + threadIdx.x;
  const unsigned short* p = lout + (size_t)bc * 512 * 512 + col;
  float s = 0.f;
  #pragma unroll 8
  for (int r = 0; r < 512; ++r) s += bf2f(p[(size_t)r * 512]);
  summ[bc * 512 + col] = s * (1.f / 512.f);
}

// ---------------- K5a: sg = summaries @ Wg.T (fp32, tiny) ----------------
__global__ __launch_bounds__(256) void k_sg(const float* __restrict__ summ,
                                            const float* __restrict__ Wg,
                                            float* __restrict__ sg) {
  __shared__ float srow[512];
  int m = blockIdx.x >> 1, half = blockIdx.x & 1;
  for (int i = threadIdx.x; i < 512; i += 256) srow[i] = summ[m * 512 + i];
  __syncthreads();
  int n = half * 256 + threadIdx.x;
  const float* wr = Wg + (size_t)n * 512;
  float s = 0.f;
  #pragma unroll 8
  for (int kk = 0; kk < 512; ++kk) s += srow[kk] * wr[kk];
  sg[m * 512 + n] = s;
}

// ---------------- K5b: cross-chunk attention (fp32, tiny): one block per (batch, head) ----------------
__global__ __launch_bounds__(256) void k_gattn(const float* __restrict__ sg,
                                               float* __restrict__ gctx) {
  __shared__ float qs[32][64];
  __shared__ float sc[32][32];
  int b = blockIdx.x >> 3, h = blockIdx.x & 7;
  int tid = threadIdx.x;
  for (int i = tid; i < 2048; i += 256) {
    int r = i >> 6, e = i & 63;
    qs[r][e] = sg[(size_t)(b * 32 + r) * 512 + h * 64 + e];
  }
  __syncthreads();
  for (int p = tid; p < 1024; p += 256) {
    int qi = p >> 5, ki = p & 31;
    float s = 0.f;
    #pragma unroll 8
    for (int e = 0; e < 64; ++e) s += qs[qi][e] * qs[ki][e];
    sc[qi][ki] = s * 0.125f;
  }
  __syncthreads();
  if (tid < 32) {
    float mx = -1e30f;
    for (int k2 = 0; k2 < 32; ++k2) mx = fmaxf(mx, sc[tid][k2]);
    float sm = 0.f;
    for (int k2 = 0; k2 < 32; ++k2) { float p = __expf(sc[tid][k2] - mx); sc[tid][k2] = p; sm += p; }
    float iv = 1.f / sm;
    for (int k2 = 0; k2 < 32; ++k2) sc[tid][k2] *= iv;
  }
  __syncthreads();
  for (int i = tid; i < 2048; i += 256) {
    int r = i >> 6, e = i & 63;
    float o = 0.f;
    #pragma unroll 8
    for (int k2 = 0; k2 < 32; ++k2) o += sc[r][k2] * qs[k2][e];
    gctx[(size_t)(b * 32 + r) * 512 + h * 64 + e] = o;
  }
}

// ---------------- K6: out = local_out + broadcast(gctx), fp32 output ----------------
__global__ __launch_bounds__(256) void k_final(const unsigned short* __restrict__ lout,
                                               const float* __restrict__ gctx,
                                               float* __restrict__ out) {
  size_t idx = (size_t)blockIdx.x * 256 + threadIdx.x;
  size_t i = idx * 4;
  int c = (int)(i & 511);
  int bcg = (int)(i >> 18);   // (i>>9) = row; row>>9 = global chunk
  ushort4 lv = *(const ushort4*)(lout + i);
  float4 g = *(const float4*)(gctx + (size_t)bcg * 512 + c);
  float4 o;
  o.x = bf2f(lv.x) + g.x;
  o.y = bf2f(lv.y) + g.y;
  o.z = bf2f(lv.z) + g.z;
  o.w = bf2f(lv.w) + g.w;
  *(float4*)(out + i) = o;
}

extern "C" void kernel_launch(void* const* d_in, const int* in_sizes, int n_in,
                              void* d_out, int out_size, void* d_ws, size_t ws_size,
                              hipStream_t stream) {
  const float* x  = (const float*)d_in[0];
  const float* Wq = (const float*)d_in[1];
  const float* Wk = (const float*)d_in[2];
  const float* Wv = (const float*)d_in[3];
  const float* Wo = (const float*)d_in[4];
  const float* Wg = (const float*)d_in[5];
  float* out = (float*)d_out;

  // workspace layout (total 136,708,096 B ≈ 130.4 MiB)
  char* ws = (char*)d_ws;
  unsigned short* xb   = (unsigned short*)(ws);                 // 32 MB  [A]
  unsigned short* q    = (unsigned short*)(ws + 33554432);      // 32 MB  [B]
  unsigned short* kb   = (unsigned short*)(ws + 67108864);      // 32 MB  [C]
  unsigned short* vt   = (unsigned short*)(ws + 100663296);     // 32 MB  [D]
  unsigned short* wqkv = (unsigned short*)(ws + 134217728);     // 1.5 MB
  unsigned short* wo_b = (unsigned short*)(ws + 135790592);     // 0.5 MB
  float* summ = (float*)(ws + 136314880);                       // 128 KB
  float* sgp  = (float*)(ws + 136445952);                       // 128 KB
  float* gctx = (float*)(ws + 136577024);                       // 128 KB
  unsigned short* attn_out = xb;   // region A reused (xb dead after k_qkv)
  unsigned short* local_bf = q;    // region B reused (q dead after k_attn)

  k_convert<<<17408, 256, 0, stream>>>(x, Wq, Wk, Wv, Wo, xb, wqkv, wo_b);
  // QKV: M=32768, N=1536 -> 256 x 12 = 3072 blocks
  k_gemm<12, 1><<<3072, 256, 0, stream>>>(xb, wqkv, q, kb, vt);
  k_attn<<<4096, 256, 0, stream>>>(q, kb, vt, attn_out);
  // Wo: M=32768, N=512 -> 256 x 4 = 1024 blocks
  k_gemm<4, 0><<<1024, 256, 0, stream>>>(attn_out, wo_b, local_bf, nullptr, nullptr);
  k_mean<<<dim3(64, 2), 256, 0, stream>>>(local_bf, summ);
  k_sg<<<128, 256, 0, stream>>>(summ, Wg, sgp);
  k_gattn<<<16, 256, 0, stream>>>(sgp, gctx);
  k_final<<<16384, 256, 0, stream>>>(local_bf, gctx, out);
}

// Round 3
// 332.036 us; speedup vs baseline: 2.8693x; 1.4843x over previous
//
#include <hip/hip_runtime.h>

typedef __attribute__((ext_vector_type(8))) short short8;
typedef __attribute__((ext_vector_type(4))) float f32x4;

#define DEV static __device__ __forceinline__

DEV float bf2f(unsigned short u) {
  union { unsigned int u32; float f; } v; v.u32 = ((unsigned int)u) << 16; return v.f;
}
DEV unsigned short f2bf(float f) {
  union { float f; unsigned int u; } v; v.f = f;
  unsigned int r = v.u + 0x7fffu + ((v.u >> 16) & 1u);
  return (unsigned short)(r >> 16);
}

// async global->LDS, 16B per lane; LDS dest is wave-uniform base + lane*16
#define GLL16(g, l) __builtin_amdgcn_global_load_lds( \
    (const __attribute__((address_space(1))) void*)(g), \
    (__attribute__((address_space(3))) void*)(l), 16, 0, 0)

constexpr int D  = 512;
constexpr int BT = 32768;   // B*T rows

// ---------------- K1: fp32 -> bf16 conversion (x, Wq|Wk|Wv concat, Wo) ----------------
__global__ __launch_bounds__(256) void k_convert(
    const float* __restrict__ x, const float* __restrict__ Wq, const float* __restrict__ Wk,
    const float* __restrict__ Wv, const float* __restrict__ Wo,
    unsigned short* __restrict__ xb, unsigned short* __restrict__ wqkv,
    unsigned short* __restrict__ wo_b) {
  int idx = blockIdx.x * 256 + threadIdx.x;
  const int NX4 = (BT * D) / 4;      // 4,194,304
  const float* src; unsigned short* dst; size_t i4;
  if (idx < NX4) {
    src = x; dst = xb; i4 = (size_t)idx * 4;
  } else {
    int t = idx - NX4;
    int w = t >> 16;                 // NW4 = 512*512/4 = 65536
    int within = t & 65535;
    src = (w == 0) ? Wq : (w == 1) ? Wk : (w == 2) ? Wv : Wo;
    dst = (w < 3) ? (wqkv + (size_t)w * D * D) : wo_b;
    i4 = (size_t)within * 4;
  }
  float4 v = *(const float4*)(src + i4);
  ushort4 o; o.x = f2bf(v.x); o.y = f2bf(v.y); o.z = f2bf(v.z); o.w = f2bf(v.w);
  *(ushort4*)(dst + i4) = o;
}

// ---------------- m97-structure GEMM: C[M,N] = A[M,512] x B[N,512]^T ----------------
template<int NBLK, int EPI>
__global__ __launch_bounds__(256) void k_gemm(
    const unsigned short* __restrict__ A, const unsigned short* __restrict__ Bm,
    unsigned short* __restrict__ O0, unsigned short* __restrict__ O1,
    unsigned short* __restrict__ O2) {
  __shared__ unsigned short Ash[128 * 32];
  __shared__ unsigned short Bsh[128 * 32];
  const int tid = threadIdx.x;
  const int lane = tid & 63, w = tid >> 6;
  const int lr = lane & 15, lg = lane >> 4;
  const int cpx = gridDim.x >> 3;
  const int bid = blockIdx.x;
  const int work = (bid & 7) * cpx + (bid >> 3);
  const int nb = work % NBLK, mb = work / NBLK;
  const int m0 = mb * 128, n0 = nb * 128;
  const int wr = w >> 1, wc = w & 1;

  const int srow = w * 32 + (lane >> 2);
  const int scol = (lane & 3) * 8;
  const unsigned short* gA = A + (size_t)(m0 + srow) * D + scol;
  const unsigned short* gB = Bm + (size_t)(n0 + srow) * D + scol;

  f32x4 acc[4][4];
  #pragma unroll
  for (int m = 0; m < 4; ++m)
    #pragma unroll
    for (int n = 0; n < 4; ++n) acc[m][n] = (f32x4){0.f, 0.f, 0.f, 0.f};

  for (int kt = 0; kt < 16; ++kt) {
    __syncthreads();
    const unsigned short* a0 = gA + kt * 32;
    const unsigned short* b0 = gB + kt * 32;
    GLL16(a0,            &Ash[w * 1024]);
    GLL16(a0 + 16 * D,   &Ash[w * 1024 + 512]);
    GLL16(b0,            &Bsh[w * 1024]);
    GLL16(b0 + 16 * D,   &Bsh[w * 1024 + 512]);
    __syncthreads();
    short8 af[4], bf[4];
    #pragma unroll
    for (int m = 0; m < 4; ++m)
      af[m] = *(const short8*)&Ash[(wr * 64 + m * 16 + lr) * 32 + lg * 8];
    #pragma unroll
    for (int n = 0; n < 4; ++n)
      bf[n] = *(const short8*)&Bsh[(wc * 64 + n * 16 + lr) * 32 + lg * 8];
    #pragma unroll
    for (int m = 0; m < 4; ++m)
      #pragma unroll
      for (int n = 0; n < 4; ++n)
        acc[m][n] = __builtin_amdgcn_mfma_f32_16x16x32_bf16(af[m], bf[n], acc[m][n], 0, 0, 0);
  }

  #pragma unroll
  for (int m = 0; m < 4; ++m) {
    #pragma unroll
    for (int n = 0; n < 4; ++n) {
      int col = n0 + wc * 64 + n * 16 + lr;
      #pragma unroll
      for (int r = 0; r < 4; ++r) {
        int row = m0 + wr * 64 + m * 16 + lg * 4 + r;
        unsigned short val = f2bf(acc[m][n][r]);
        if (EPI == 0) {
          O0[(size_t)row * D + col] = val;
        } else {
          if (col < 512)       O0[(size_t)row * D + col] = val;
          else if (col < 1024) O1[(size_t)row * D + (col - 512)] = val;
          else {
            int e = col - 1024, bc = row >> 9, key = row & 511;
            O2[(size_t)(bc * 512 + e) * 512 + key] = val;   // Vt[bc][feature][key]
          }
        }
      }
    }
  }
}

// ---------------- K3: local attention with LDS-staged K/V tiles ----------------
// grid = 4096 = 64 chunks x 8 heads x 8 q-blocks; block = 256 (4 waves x 16 q-rows)
// LDS: 2 x 16KB KV dbuf (K-phase & V-phase time-share it) + 4 x 4KB per-wave P = 48KB
__global__ __launch_bounds__(256, 2) void k_attn(
    const unsigned short* __restrict__ Q, const unsigned short* __restrict__ K,
    const unsigned short* __restrict__ Vt, unsigned short* __restrict__ attn_out) {
  __shared__ char kv[2][16384];
  __shared__ char plds[4][4096];
  int lane = threadIdx.x & 63, w = threadIdx.x >> 6;
  int lr = lane & 15, lg = lane >> 4;
  // XCD swizzle: 512 consecutive works (8 chunks' worth) per XCD -> K/V slices L2-resident
  int work = ((blockIdx.x & 7) << 9) + (blockIdx.x >> 3);
  int qb = work & 7, h = (work >> 3) & 7, bc = work >> 6;
  int qrow0 = bc * 512 + qb * 64 + w * 16;
  const int kvrow0 = bc * 512;            // K rows for this chunk
  const int vrow0  = bc * 512 + h * 64;   // Vt rows for this (chunk, head)

  const unsigned short* qp = Q + (size_t)(qrow0 + lr) * D + h * 64 + lg * 8;
  short8 aq0 = *(const short8*)(qp);
  short8 aq1 = *(const short8*)(qp + 32);

  // ---- staging helpers (pre-swizzled global source, linear LDS dest) ----
  // K tile kt: LDS [128 keys][64 dims], row = 128B, swz byte ^= (row&7)<<4
  // wave w stages rows w*32 + c*8 .. +8 (4 calls x 1KB)
  auto stageK = [&](int kt, char* buf) {
    #pragma unroll
    for (int c = 0; c < 4; ++c) {
      int r0 = w * 32 + c * 8;
      int row = r0 + (lane >> 3);
      int ecol = ((lane & 7) ^ (lane >> 3)) * 8;
      const unsigned short* src = K + (size_t)(kvrow0 + kt * 128 + row) * D + h * 64 + ecol;
      GLL16(src, buf + r0 * 128);
    }
  };
  // Vt tile kt: LDS [64 dims][128 keys], row = 256B, swz byte ^= (row&7)<<4
  // wave w stages rows w*16 + c*4 .. +4 (4 calls x 1KB)
  auto stageV = [&](int kt, char* buf) {
    #pragma unroll
    for (int c = 0; c < 4; ++c) {
      int r0 = w * 16 + c * 4;
      int row = r0 + (lane >> 4);
      int cb = ((lane & 15) * 16) ^ ((row & 7) << 4);
      const unsigned short* src = Vt + (size_t)(vrow0 + row) * D + kt * 128 + (cb >> 1);
      GLL16(src, buf + r0 * 256);
    }
  };

  f32x4 acc[32];
  #pragma unroll
  for (int i = 0; i < 32; ++i) acc[i] = (f32x4){0.f, 0.f, 0.f, 0.f};

  // ---- QK^T: 4 K-tiles of 128 keys, double-buffered ----
  stageK(0, kv[0]);
  __syncthreads();
  #pragma unroll
  for (int kt = 0; kt < 4; ++kt) {
    if (kt < 3) stageK(kt + 1, kv[(kt + 1) & 1]);
    const char* kb = kv[kt & 1];
    #pragma unroll
    for (int nt = 0; nt < 8; ++nt) {
      int row = nt * 16 + lr;
      int rb = row * 128;
      int s = (lr & 7) << 4;
      short8 b0 = *(const short8*)(kb + ((rb + lg * 16) ^ s));
      short8 b1 = *(const short8*)(kb + ((rb + 64 + lg * 16) ^ s));
      acc[kt * 8 + nt] = __builtin_amdgcn_mfma_f32_16x16x32_bf16(aq0, b0, acc[kt * 8 + nt], 0, 0, 0);
      acc[kt * 8 + nt] = __builtin_amdgcn_mfma_f32_16x16x32_bf16(aq1, b1, acc[kt * 8 + nt], 0, 0, 0);
    }
    __syncthreads();
  }

  // ---- stage Vt tile 0 early: hides under the pure-VALU softmax ----
  stageV(0, kv[0]);

  // ---- exact softmax on acc[32] (rows = lg*4+r), fp32 ----
  float rmax[4] = {-1e30f, -1e30f, -1e30f, -1e30f};
  #pragma unroll
  for (int nt = 0; nt < 32; ++nt) {
    #pragma unroll
    for (int r = 0; r < 4; ++r) rmax[r] = fmaxf(rmax[r], acc[nt][r]);
  }
  #pragma unroll
  for (int r = 0; r < 4; ++r) {
    #pragma unroll
    for (int m = 1; m < 16; m <<= 1) rmax[r] = fmaxf(rmax[r], __shfl_xor(rmax[r], m));
  }
  const float scale = 0.125f;   // 1/sqrt(64)
  float rsum[4] = {0.f, 0.f, 0.f, 0.f};
  #pragma unroll
  for (int nt = 0; nt < 32; ++nt) {
    #pragma unroll
    for (int r = 0; r < 4; ++r) {
      float p = __expf((acc[nt][r] - rmax[r]) * scale);
      acc[nt][r] = p; rsum[r] += p;
    }
  }
  #pragma unroll
  for (int r = 0; r < 4; ++r) {
    #pragma unroll
    for (int m = 1; m < 16; m <<= 1) rsum[r] += __shfl_xor(rsum[r], m);
  }
  __syncthreads();   // Vt tile 0 staged, all waves ready

  // ---- PV: 4 Vt-tiles of 128 keys, double-buffered; P slice via per-wave LDS ----
  char* pb = plds[w];
  f32x4 oacc[4];
  #pragma unroll
  for (int j = 0; j < 4; ++j) oacc[j] = (f32x4){0.f, 0.f, 0.f, 0.f};
  #pragma unroll
  for (int kt = 0; kt < 4; ++kt) {
    if (kt < 3) stageV(kt + 1, kv[(kt + 1) & 1]);
    // write this tile's P slice (16 q x 128 keys, bf16, swizzled)
    #pragma unroll
    for (int nt = 0; nt < 8; ++nt) {
      #pragma unroll
      for (int r = 0; r < 4; ++r) {
        int prow = lg * 4 + r, pcol = nt * 16 + lr;
        int byt = (prow * 256 + pcol * 2) ^ ((prow & 7) << 4);
        *(unsigned short*)(pb + byt) = f2bf(acc[kt * 8 + nt][r]);
      }
    }
    const char* vb = kv[kt & 1];
    #pragma unroll
    for (int kk = 0; kk < 4; ++kk) {
      short8 a = *(const short8*)(pb + ((lr * 256 + kk * 64 + lg * 16) ^ ((lr & 7) << 4)));
      #pragma unroll
      for (int j = 0; j < 4; ++j) {
        int row = j * 16 + lr;
        short8 b = *(const short8*)(vb + ((row * 256 + kk * 64 + lg * 16) ^ ((row & 7) << 4)));
        oacc[j] = __builtin_amdgcn_mfma_f32_16x16x32_bf16(a, b, oacc[j], 0, 0, 0);
      }
    }
    __syncthreads();
  }

  float inv[4];
  #pragma unroll
  for (int r = 0; r < 4; ++r) inv[r] = 1.f / rsum[r];
  #pragma unroll
  for (int j = 0; j < 4; ++j) {
    int col = h * 64 + j * 16 + lr;
    #pragma unroll
    for (int r = 0; r < 4; ++r) {
      int row = qrow0 + lg * 4 + r;
      attn_out[(size_t)row * D + col] = f2bf(oacc[j][r] * inv[r]);
    }
  }
}

// ---------------- K4b: per-chunk mean -> summaries fp32 [64][512] ----------------
__global__ __launch_bounds__(256) void k_mean(const unsigned short* __restrict__ lout,
                                              float* __restrict__ summ) {
  int bc = blockIdx.x;
  int col = blockIdx.y * 256 + threadIdx.x;
  const unsigned short* p = lout + (size_t)bc * 512 * 512 + col;
  float s = 0.f;
  #pragma unroll 8
  for (int r = 0; r < 512; ++r) s += bf2f(p[(size_t)r * 512]);
  summ[bc * 512 + col] = s * (1.f / 512.f);
}

// ---------------- K5a: sg = summaries @ Wg.T (fp32, tiny) ----------------
__global__ __launch_bounds__(256) void k_sg(const float* __restrict__ summ,
                                            const float* __restrict__ Wg,
                                            float* __restrict__ sg) {
  __shared__ float srow[512];
  int m = blockIdx.x >> 1, half = blockIdx.x & 1;
  for (int i = threadIdx.x; i < 512; i += 256) srow[i] = summ[m * 512 + i];
  __syncthreads();
  int n = half * 256 + threadIdx.x;
  const float* wr = Wg + (size_t)n * 512;
  float s = 0.f;
  #pragma unroll 8
  for (int kk = 0; kk < 512; ++kk) s += srow[kk] * wr[kk];
  sg[m * 512 + n] = s;
}

// ---------------- K5b: cross-chunk attention (fp32, tiny) ----------------
__global__ __launch_bounds__(256) void k_gattn(const float* __restrict__ sg,
                                               float* __restrict__ gctx) {
  __shared__ float qs[32][64];
  __shared__ float sc[32][32];
  int b = blockIdx.x >> 3, h = blockIdx.x & 7;
  int tid = threadIdx.x;
  for (int i = tid; i < 2048; i += 256) {
    int r = i >> 6, e = i & 63;
    qs[r][e] = sg[(size_t)(b * 32 + r) * 512 + h * 64 + e];
  }
  __syncthreads();
  for (int p = tid; p < 1024; p += 256) {
    int qi = p >> 5, ki = p & 31;
    float s = 0.f;
    #pragma unroll 8
    for (int e = 0; e < 64; ++e) s += qs[qi][e] * qs[ki][e];
    sc[qi][ki] = s * 0.125f;
  }
  __syncthreads();
  if (tid < 32) {
    float mx = -1e30f;
    for (int k2 = 0; k2 < 32; ++k2) mx = fmaxf(mx, sc[tid][k2]);
    float sm = 0.f;
    for (int k2 = 0; k2 < 32; ++k2) { float p = __expf(sc[tid][k2] - mx); sc[tid][k2] = p; sm += p; }
    float iv = 1.f / sm;
    for (int k2 = 0; k2 < 32; ++k2) sc[tid][k2] *= iv;
  }
  __syncthreads();
  for (int i = tid; i < 2048; i += 256) {
    int r = i >> 6, e = i & 63;
    float o = 0.f;
    #pragma unroll 8
    for (int k2 = 0; k2 < 32; ++k2) o += sc[r][k2] * qs[k2][e];
    gctx[(size_t)(b * 32 + r) * 512 + h * 64 + e] = o;
  }
}

// ---------------- K6: out = local_out + broadcast(gctx), fp32 output ----------------
__global__ __launch_bounds__(256) void k_final(const unsigned short* __restrict__ lout,
                                               const float* __restrict__ gctx,
                                               float* __restrict__ out) {
  size_t idx = (size_t)blockIdx.x * 256 + threadIdx.x;
  size_t i = idx * 4;
  int c = (int)(i & 511);
  int bcg = (int)(i >> 18);
  ushort4 lv = *(const ushort4*)(lout + i);
  float4 g = *(const float4*)(gctx + (size_t)bcg * 512 + c);
  float4 o;
  o.x = bf2f(lv.x) + g.x;
  o.y = bf2f(lv.y) + g.y;
  o.z = bf2f(lv.z) + g.z;
  o.w = bf2f(lv.w) + g.w;
  *(float4*)(out + i) = o;
}

extern "C" void kernel_launch(void* const* d_in, const int* in_sizes, int n_in,
                              void* d_out, int out_size, void* d_ws, size_t ws_size,
                              hipStream_t stream) {
  const float* x  = (const float*)d_in[0];
  const float* Wq = (const float*)d_in[1];
  const float* Wk = (const float*)d_in[2];
  const float* Wv = (const float*)d_in[3];
  const float* Wo = (const float*)d_in[4];
  const float* Wg = (const float*)d_in[5];
  float* out = (float*)d_out;

  char* ws = (char*)d_ws;
  unsigned short* xb   = (unsigned short*)(ws);                 // 32 MB  [A]
  unsigned short* q    = (unsigned short*)(ws + 33554432);      // 32 MB  [B]
  unsigned short* kb   = (unsigned short*)(ws + 67108864);      // 32 MB  [C]
  unsigned short* vt   = (unsigned short*)(ws + 100663296);     // 32 MB  [D]
  unsigned short* wqkv = (unsigned short*)(ws + 134217728);     // 1.5 MB
  unsigned short* wo_b = (unsigned short*)(ws + 135790592);     // 0.5 MB
  float* summ = (float*)(ws + 136314880);                       // 128 KB
  float* sgp  = (float*)(ws + 136445952);                       // 128 KB
  float* gctx = (float*)(ws + 136577024);                       // 128 KB
  unsigned short* attn_out = xb;   // region A reused (xb dead after k_qkv)
  unsigned short* local_bf = q;    // region B reused (q dead after k_attn)

  k_convert<<<17408, 256, 0, stream>>>(x, Wq, Wk, Wv, Wo, xb, wqkv, wo_b);
  k_gemm<12, 1><<<3072, 256, 0, stream>>>(xb, wqkv, q, kb, vt);
  k_attn<<<4096, 256, 0, stream>>>(q, kb, vt, attn_out);
  k_gemm<4, 0><<<1024, 256, 0, stream>>>(attn_out, wo_b, local_bf, nullptr, nullptr);
  k_mean<<<dim3(64, 2), 256, 0, stream>>>(local_bf, summ);
  k_sg<<<128, 256, 0, stream>>>(summ, Wg, sgp);
  k_gattn<<<16, 256, 0, stream>>>(sgp, gctx);
  k_final<<<16384, 256, 0, stream>>>(local_bf, gctx, out);
}

// Round 4
// 318.696 us; speedup vs baseline: 2.9894x; 1.0419x over previous
//
#include <hip/hip_runtime.h>

typedef __attribute__((ext_vector_type(8))) short short8;
typedef __attribute__((ext_vector_type(4))) float f32x4;

#define DEV static __device__ __forceinline__

DEV float bf2f(unsigned short u) {
  union { unsigned int u32; float f; } v; v.u32 = ((unsigned int)u) << 16; return v.f;
}
DEV unsigned short f2bf(float f) {
  union { float f; unsigned int u; } v; v.f = f;
  unsigned int r = v.u + 0x7fffu + ((v.u >> 16) & 1u);
  return (unsigned short)(r >> 16);
}

// async global->LDS, 16B per lane; LDS dest is wave-uniform base + lane*16
#define GLL16(g, l) __builtin_amdgcn_global_load_lds( \
    (const __attribute__((address_space(1))) void*)(g), \
    (__attribute__((address_space(3))) void*)(l), 16, 0, 0)

constexpr int D  = 512;
constexpr int BT = 32768;   // B*T rows

// ---------------- K1: fp32 -> bf16 conversion (x, Wq|Wk|Wv concat, Wo) ----------------
__global__ __launch_bounds__(256) void k_convert(
    const float* __restrict__ x, const float* __restrict__ Wq, const float* __restrict__ Wk,
    const float* __restrict__ Wv, const float* __restrict__ Wo,
    unsigned short* __restrict__ xb, unsigned short* __restrict__ wqkv,
    unsigned short* __restrict__ wo_b) {
  int idx = blockIdx.x * 256 + threadIdx.x;
  const int NX4 = (BT * D) / 4;      // 4,194,304
  const float* src; unsigned short* dst; size_t i4;
  if (idx < NX4) {
    src = x; dst = xb; i4 = (size_t)idx * 4;
  } else {
    int t = idx - NX4;
    int w = t >> 16;                 // NW4 = 512*512/4 = 65536
    int within = t & 65535;
    src = (w == 0) ? Wq : (w == 1) ? Wk : (w == 2) ? Wv : Wo;
    dst = (w < 3) ? (wqkv + (size_t)w * D * D) : wo_b;
    i4 = (size_t)within * 4;
  }
  float4 v = *(const float4*)(src + i4);
  ushort4 o; o.x = f2bf(v.x); o.y = f2bf(v.y); o.z = f2bf(v.z); o.w = f2bf(v.w);
  *(ushort4*)(dst + i4) = o;
}

// ---------------- 2-phase prefetch GEMM: C[M,N] = A[M,512] x B[N,512]^T ----------------
// 128x128 tile, BK=32, 4 waves (2x2), double-buffered LDS, stage(kt+1) issued BEFORE
// compute(kt); single vmcnt(0)+s_barrier per K-step AFTER compute (T3 minimum recipe).
template<int NBLK, int EPI>
__global__ __launch_bounds__(256) void k_gemm(
    const unsigned short* __restrict__ A, const unsigned short* __restrict__ Bm,
    unsigned short* __restrict__ O0, unsigned short* __restrict__ O1,
    unsigned short* __restrict__ O2) {
  __shared__ unsigned short Ash[2][128 * 32];
  __shared__ unsigned short Bsh[2][128 * 32];
  const int tid = threadIdx.x;
  const int lane = tid & 63, w = tid >> 6;
  const int lr = lane & 15, lg = lane >> 4;
  // bijective XCD-chunked swizzle (gridDim %8 == 0 for all instantiations)
  const int cpx = gridDim.x >> 3;
  const int bid = blockIdx.x;
  const int work = (bid & 7) * cpx + (bid >> 3);
  const int nb = work % NBLK, mb = work / NBLK;
  const int m0 = mb * 128, n0 = nb * 128;
  const int wr = w >> 1, wc = w & 1;

  // staging: wave w fills rows w*32..w*32+31 of both tiles (4 x GLL16, 16B/lane)
  const int srow = w * 32 + (lane >> 2);
  const int scol = (lane & 3) * 8;
  const unsigned short* gA = A + (size_t)(m0 + srow) * D + scol;
  const unsigned short* gB = Bm + (size_t)(n0 + srow) * D + scol;

  f32x4 acc[4][4];
  #pragma unroll
  for (int m = 0; m < 4; ++m)
    #pragma unroll
    for (int n = 0; n < 4; ++n) acc[m][n] = (f32x4){0.f, 0.f, 0.f, 0.f};

  auto stage = [&](int kt, int buf) {
    const unsigned short* a0 = gA + kt * 32;
    const unsigned short* b0 = gB + kt * 32;
    GLL16(a0,          &Ash[buf][w * 1024]);
    GLL16(a0 + 16 * D, &Ash[buf][w * 1024 + 512]);
    GLL16(b0,          &Bsh[buf][w * 1024]);
    GLL16(b0 + 16 * D, &Bsh[buf][w * 1024 + 512]);
  };

  // prologue: tile 0 staged and visible
  stage(0, 0);
  asm volatile("s_waitcnt vmcnt(0)" ::: "memory");
  __builtin_amdgcn_s_barrier();

  for (int kt = 0; kt < 16; ++kt) {
    const int cur = kt & 1;
    if (kt < 15) stage(kt + 1, cur ^ 1);   // issue next-tile loads FIRST (overlap)
    short8 af[4], bf[4];
    #pragma unroll
    for (int m = 0; m < 4; ++m)
      af[m] = *(const short8*)&Ash[cur][(wr * 64 + m * 16 + lr) * 32 + lg * 8];
    #pragma unroll
    for (int n = 0; n < 4; ++n)
      bf[n] = *(const short8*)&Bsh[cur][(wc * 64 + n * 16 + lr) * 32 + lg * 8];
    __builtin_amdgcn_s_setprio(1);
    #pragma unroll
    for (int m = 0; m < 4; ++m)
      #pragma unroll
      for (int n = 0; n < 4; ++n)
        acc[m][n] = __builtin_amdgcn_mfma_f32_16x16x32_bf16(af[m], bf[n], acc[m][n], 0, 0, 0);
    __builtin_amdgcn_s_setprio(0);
    if (kt < 15) {
      asm volatile("s_waitcnt vmcnt(0)" ::: "memory");  // next tile landed
      __builtin_amdgcn_s_barrier();                     // all waves: safe to read buf^1
    }
  }

  #pragma unroll
  for (int m = 0; m < 4; ++m) {
    #pragma unroll
    for (int n = 0; n < 4; ++n) {
      int col = n0 + wc * 64 + n * 16 + lr;
      #pragma unroll
      for (int r = 0; r < 4; ++r) {
        int row = m0 + wr * 64 + m * 16 + lg * 4 + r;
        unsigned short val = f2bf(acc[m][n][r]);
        if (EPI == 0) {
          O0[(size_t)row * D + col] = val;
        } else {
          if (col < 512)       O0[(size_t)row * D + col] = val;
          else if (col < 1024) O1[(size_t)row * D + (col - 512)] = val;
          else {
            int e = col - 1024, bc = row >> 9, key = row & 511;
            O2[(size_t)(bc * 512 + e) * 512 + key] = val;   // Vt[bc][feature][key]
          }
        }
      }
    }
  }
}

// ---------------- K3: local attention with LDS-staged K/V tiles ----------------
// grid = 4096 = 64 chunks x 8 heads x 8 q-blocks; block = 256 (4 waves x 16 q-rows)
__global__ __launch_bounds__(256, 2) void k_attn(
    const unsigned short* __restrict__ Q, const unsigned short* __restrict__ K,
    const unsigned short* __restrict__ Vt, unsigned short* __restrict__ attn_out) {
  __shared__ char kv[2][16384];
  __shared__ char plds[4][4096];
  int lane = threadIdx.x & 63, w = threadIdx.x >> 6;
  int lr = lane & 15, lg = lane >> 4;
  int work = ((blockIdx.x & 7) << 9) + (blockIdx.x >> 3);
  int qb = work & 7, h = (work >> 3) & 7, bc = work >> 6;
  int qrow0 = bc * 512 + qb * 64 + w * 16;
  const int kvrow0 = bc * 512;
  const int vrow0  = bc * 512 + h * 64;

  const unsigned short* qp = Q + (size_t)(qrow0 + lr) * D + h * 64 + lg * 8;
  short8 aq0 = *(const short8*)(qp);
  short8 aq1 = *(const short8*)(qp + 32);

  auto stageK = [&](int kt, char* buf) {
    #pragma unroll
    for (int c = 0; c < 4; ++c) {
      int r0 = w * 32 + c * 8;
      int row = r0 + (lane >> 3);
      int ecol = ((lane & 7) ^ (lane >> 3)) * 8;
      const unsigned short* src = K + (size_t)(kvrow0 + kt * 128 + row) * D + h * 64 + ecol;
      GLL16(src, buf + r0 * 128);
    }
  };
  auto stageV = [&](int kt, char* buf) {
    #pragma unroll
    for (int c = 0; c < 4; ++c) {
      int r0 = w * 16 + c * 4;
      int row = r0 + (lane >> 4);
      int cb = ((lane & 15) * 16) ^ ((row & 7) << 4);
      const unsigned short* src = Vt + (size_t)(vrow0 + row) * D + kt * 128 + (cb >> 1);
      GLL16(src, buf + r0 * 256);
    }
  };

  f32x4 acc[32];
  #pragma unroll
  for (int i = 0; i < 32; ++i) acc[i] = (f32x4){0.f, 0.f, 0.f, 0.f};

  stageK(0, kv[0]);
  __syncthreads();
  #pragma unroll
  for (int kt = 0; kt < 4; ++kt) {
    if (kt < 3) stageK(kt + 1, kv[(kt + 1) & 1]);
    const char* kb = kv[kt & 1];
    #pragma unroll
    for (int nt = 0; nt < 8; ++nt) {
      int row = nt * 16 + lr;
      int rb = row * 128;
      int s = (lr & 7) << 4;
      short8 b0 = *(const short8*)(kb + ((rb + lg * 16) ^ s));
      short8 b1 = *(const short8*)(kb + ((rb + 64 + lg * 16) ^ s));
      acc[kt * 8 + nt] = __builtin_amdgcn_mfma_f32_16x16x32_bf16(aq0, b0, acc[kt * 8 + nt], 0, 0, 0);
      acc[kt * 8 + nt] = __builtin_amdgcn_mfma_f32_16x16x32_bf16(aq1, b1, acc[kt * 8 + nt], 0, 0, 0);
    }
    __syncthreads();
  }

  stageV(0, kv[0]);

  float rmax[4] = {-1e30f, -1e30f, -1e30f, -1e30f};
  #pragma unroll
  for (int nt = 0; nt < 32; ++nt) {
    #pragma unroll
    for (int r = 0; r < 4; ++r) rmax[r] = fmaxf(rmax[r], acc[nt][r]);
  }
  #pragma unroll
  for (int r = 0; r < 4; ++r) {
    #pragma unroll
    for (int m = 1; m < 16; m <<= 1) rmax[r] = fmaxf(rmax[r], __shfl_xor(rmax[r], m));
  }
  const float scale = 0.125f;   // 1/sqrt(64)
  float rsum[4] = {0.f, 0.f, 0.f, 0.f};
  #pragma unroll
  for (int nt = 0; nt < 32; ++nt) {
    #pragma unroll
    for (int r = 0; r < 4; ++r) {
      float p = __expf((acc[nt][r] - rmax[r]) * scale);
      acc[nt][r] = p; rsum[r] += p;
    }
  }
  #pragma unroll
  for (int r = 0; r < 4; ++r) {
    #pragma unroll
    for (int m = 1; m < 16; m <<= 1) rsum[r] += __shfl_xor(rsum[r], m);
  }
  __syncthreads();

  char* pb = plds[w];
  f32x4 oacc[4];
  #pragma unroll
  for (int j = 0; j < 4; ++j) oacc[j] = (f32x4){0.f, 0.f, 0.f, 0.f};
  #pragma unroll
  for (int kt = 0; kt < 4; ++kt) {
    if (kt < 3) stageV(kt + 1, kv[(kt + 1) & 1]);
    #pragma unroll
    for (int nt = 0; nt < 8; ++nt) {
      #pragma unroll
      for (int r = 0; r < 4; ++r) {
        int prow = lg * 4 + r, pcol = nt * 16 + lr;
        int byt = (prow * 256 + pcol * 2) ^ ((prow & 7) << 4);
        *(unsigned short*)(pb + byt) = f2bf(acc[kt * 8 + nt][r]);
      }
    }
    const char* vb = kv[kt & 1];
    #pragma unroll
    for (int kk = 0; kk < 4; ++kk) {
      short8 a = *(const short8*)(pb + ((lr * 256 + kk * 64 + lg * 16) ^ ((lr & 7) << 4)));
      #pragma unroll
      for (int j = 0; j < 4; ++j) {
        int row = j * 16 + lr;
        short8 b = *(const short8*)(vb + ((row * 256 + kk * 64 + lg * 16) ^ ((row & 7) << 4)));
        oacc[j] = __builtin_amdgcn_mfma_f32_16x16x32_bf16(a, b, oacc[j], 0, 0, 0);
      }
    }
    __syncthreads();
  }

  float inv[4];
  #pragma unroll
  for (int r = 0; r < 4; ++r) inv[r] = 1.f / rsum[r];
  #pragma unroll
  for (int j = 0; j < 4; ++j) {
    int col = h * 64 + j * 16 + lr;
    #pragma unroll
    for (int r = 0; r < 4; ++r) {
      int row = qrow0 + lg * 4 + r;
      attn_out[(size_t)row * D + col] = f2bf(oacc[j][r] * inv[r]);
    }
  }
}

// ---------------- K4b: per-chunk mean -> summaries fp32 [64][512] ----------------
__global__ __launch_bounds__(256) void k_mean(const unsigned short* __restrict__ lout,
                                              float* __restrict__ summ) {
  int bc = blockIdx.x;
  int col = blockIdx.y * 256 + threadIdx.x;
  const unsigned short* p = lout + (size_t)bc * 512 * 512 + col;
  float s = 0.f;
  #pragma unroll 8
  for (int r = 0; r < 512; ++r) s += bf2f(p[(size_t)r * 512]);
  summ[bc * 512 + col] = s * (1.f / 512.f);
}

// ---------------- K5a: sg = summaries @ Wg.T (fp32, tiny) ----------------
__global__ __launch_bounds__(256) void k_sg(const float* __restrict__ summ,
                                            const float* __restrict__ Wg,
                                            float* __restrict__ sg) {
  __shared__ float srow[512];
  int m = blockIdx.x >> 1, half = blockIdx.x & 1;
  for (int i = threadIdx.x; i < 512; i += 256) srow[i] = summ[m * 512 + i];
  __syncthreads();
  int n = half * 256 + threadIdx.x;
  const float* wr = Wg + (size_t)n * 512;
  float s = 0.f;
  #pragma unroll 8
  for (int kk = 0; kk < 512; ++kk) s += srow[kk] * wr[kk];
  sg[m * 512 + n] = s;
}

// ---------------- K5b: cross-chunk attention (fp32, tiny) ----------------
__global__ __launch_bounds__(256) void k_gattn(const float* __restrict__ sg,
                                               float* __restrict__ gctx) {
  __shared__ float qs[32][64];
  __shared__ float sc[32][32];
  int b = blockIdx.x >> 3, h = blockIdx.x & 7;
  int tid = threadIdx.x;
  for (int i = tid; i < 2048; i += 256) {
    int r = i >> 6, e = i & 63;
    qs[r][e] = sg[(size_t)(b * 32 + r) * 512 + h * 64 + e];
  }
  __syncthreads();
  for (int p = tid; p < 1024; p += 256) {
    int qi = p >> 5, ki = p & 31;
    float s = 0.f;
    #pragma unroll 8
    for (int e = 0; e < 64; ++e) s += qs[qi][e] * qs[ki][e];
    sc[qi][ki] = s * 0.125f;
  }
  __syncthreads();
  if (tid < 32) {
    float mx = -1e30f;
    for (int k2 = 0; k2 < 32; ++k2) mx = fmaxf(mx, sc[tid][k2]);
    float sm = 0.f;
    for (int k2 = 0; k2 < 32; ++k2) { float p = __expf(sc[tid][k2] - mx); sc[tid][k2] = p; sm += p; }
    float iv = 1.f / sm;
    for (int k2 = 0; k2 < 32; ++k2) sc[tid][k2] *= iv;
  }
  __syncthreads();
  for (int i = tid; i < 2048; i += 256) {
    int r = i >> 6, e = i & 63;
    float o = 0.f;
    #pragma unroll 8
    for (int k2 = 0; k2 < 32; ++k2) o += sc[r][k2] * qs[k2][e];
    gctx[(size_t)(b * 32 + r) * 512 + h * 64 + e] = o;
  }
}

// ---------------- K6: out = local_out + broadcast(gctx), fp32 output ----------------
__global__ __launch_bounds__(256) void k_final(const unsigned short* __restrict__ lout,
                                               const float* __restrict__ gctx,
                                               float* __restrict__ out) {
  size_t idx = (size_t)blockIdx.x * 256 + threadIdx.x;
  size_t i = idx * 4;
  int c = (int)(i & 511);
  int bcg = (int)(i >> 18);
  ushort4 lv = *(const ushort4*)(lout + i);
  float4 g = *(const float4*)(gctx + (size_t)bcg * 512 + c);
  float4 o;
  o.x = bf2f(lv.x) + g.x;
  o.y = bf2f(lv.y) + g.y;
  o.z = bf2f(lv.z) + g.z;
  o.w = bf2f(lv.w) + g.w;
  *(float4*)(out + i) = o;
}

extern "C" void kernel_launch(void* const* d_in, const int* in_sizes, int n_in,
                              void* d_out, int out_size, void* d_ws, size_t ws_size,
                              hipStream_t stream) {
  const float* x  = (const float*)d_in[0];
  const float* Wq = (const float*)d_in[1];
  const float* Wk = (const float*)d_in[2];
  const float* Wv = (const float*)d_in[3];
  const float* Wo = (const float*)d_in[4];
  const float* Wg = (const float*)d_in[5];
  float* out = (float*)d_out;

  char* ws = (char*)d_ws;
  unsigned short* xb   = (unsigned short*)(ws);                 // 32 MB  [A]
  unsigned short* q    = (unsigned short*)(ws + 33554432);      // 32 MB  [B]
  unsigned short* kb   = (unsigned short*)(ws + 67108864);      // 32 MB  [C]
  unsigned short* vt   = (unsigned short*)(ws + 100663296);     // 32 MB  [D]
  unsigned short* wqkv = (unsigned short*)(ws + 134217728);     // 1.5 MB
  unsigned short* wo_b = (unsigned short*)(ws + 135790592);     // 0.5 MB
  float* summ = (float*)(ws + 136314880);                       // 128 KB
  float* sgp  = (float*)(ws + 136445952);                       // 128 KB
  float* gctx = (float*)(ws + 136577024);                       // 128 KB
  unsigned short* attn_out = xb;   // region A reused (xb dead after k_qkv)
  unsigned short* local_bf = q;    // region B reused (q dead after k_attn)

  k_convert<<<17408, 256, 0, stream>>>(x, Wq, Wk, Wv, Wo, xb, wqkv, wo_b);
  k_gemm<12, 1><<<3072, 256, 0, stream>>>(xb, wqkv, q, kb, vt);
  k_attn<<<4096, 256, 0, stream>>>(q, kb, vt, attn_out);
  k_gemm<4, 0><<<1024, 256, 0, stream>>>(attn_out, wo_b, local_bf, nullptr, nullptr);
  k_mean<<<dim3(64, 2), 256, 0, stream>>>(local_bf, summ);
  k_sg<<<128, 256, 0, stream>>>(summ, Wg, sgp);
  k_gattn<<<16, 256, 0, stream>>>(sgp, gctx);
  k_final<<<16384, 256, 0, stream>>>(local_bf, gctx, out);
}

// Round 5
// 294.976 us; speedup vs baseline: 3.2298x; 1.0804x over previous
//
#include <hip/hip_runtime.h>

typedef __attribute__((ext_vector_type(8))) short short8;
typedef __attribute__((ext_vector_type(4))) float f32x4;

#define DEV static __device__ __forceinline__

DEV float bf2f(unsigned short u) {
  union { unsigned int u32; float f; } v; v.u32 = ((unsigned int)u) << 16; return v.f;
}
DEV unsigned short f2bf(float f) {
  union { float f; unsigned int u; } v; v.f = f;
  unsigned int r = v.u + 0x7fffu + ((v.u >> 16) & 1u);
  return (unsigned short)(r >> 16);
}

// async global->LDS, 16B per lane; LDS dest is wave-uniform base + lane*16
#define GLL16(g, l) __builtin_amdgcn_global_load_lds( \
    (const __attribute__((address_space(1))) void*)(g), \
    (__attribute__((address_space(3))) void*)(l), 16, 0, 0)

constexpr int D  = 512;
constexpr int BT = 32768;   // B*T rows

// ---------------- K1: fp32 -> bf16 conversion (x, Wq|Wk|Wv concat, Wo) ----------------
__global__ __launch_bounds__(256) void k_convert(
    const float* __restrict__ x, const float* __restrict__ Wq, const float* __restrict__ Wk,
    const float* __restrict__ Wv, const float* __restrict__ Wo,
    unsigned short* __restrict__ xb, unsigned short* __restrict__ wqkv,
    unsigned short* __restrict__ wo_b) {
  int idx = blockIdx.x * 256 + threadIdx.x;
  const int NX4 = (BT * D) / 4;      // 4,194,304
  const float* src; unsigned short* dst; size_t i4;
  if (idx < NX4) {
    src = x; dst = xb; i4 = (size_t)idx * 4;
  } else {
    int t = idx - NX4;
    int w = t >> 16;                 // NW4 = 512*512/4 = 65536
    int within = t & 65535;
    src = (w == 0) ? Wq : (w == 1) ? Wk : (w == 2) ? Wv : Wo;
    dst = (w < 3) ? (wqkv + (size_t)w * D * D) : wo_b;
    i4 = (size_t)within * 4;
  }
  float4 v = *(const float4*)(src + i4);
  ushort4 o; o.x = f2bf(v.x); o.y = f2bf(v.y); o.z = f2bf(v.z); o.w = f2bf(v.w);
  *(ushort4*)(dst + i4) = o;
}

// ---------------- deep-pipelined GEMM: C[M,N] = A[M,512] x B[N,512]^T ----------------
// 128x128 tile, BK=32, 4 waves (2x2), FOUR LDS buffers, prefetch depth 3,
// counted vmcnt(8) in steady state (T4: never drain to 0 in the main loop).
// LDS tiles XOR-swizzled 4-slot (both sides, rule #21): 8-way -> 4-way read conflict.
// EPI 0: C -> O0 row-major bf16. EPI 1: QKV scatter (per-block-uniform by nb):
//   nb 0-3 -> Q, 4-7 -> K, 8-11 -> Vt[bc][e][key] with ushort4-packed key runs.
template<int NBLK, int EPI>
__global__ __launch_bounds__(256) void k_gemm(
    const unsigned short* __restrict__ A, const unsigned short* __restrict__ Bm,
    unsigned short* __restrict__ O0, unsigned short* __restrict__ O1,
    unsigned short* __restrict__ O2) {
  __shared__ unsigned short Ash[4][128 * 32];   // 32 KB
  __shared__ unsigned short Bsh[4][128 * 32];   // 32 KB
  const int tid = threadIdx.x;
  const int lane = tid & 63, w = tid >> 6;
  const int lr = lane & 15, lg = lane >> 4;
  // bijective XCD-chunked swizzle (gridDim %8 == 0 for all instantiations)
  const int cpx = gridDim.x >> 3;
  const int bid = blockIdx.x;
  const int work = (bid & 7) * cpx + (bid >> 3);
  const int nb = work % NBLK, mb = work / NBLK;
  const int m0 = mb * 128, n0 = nb * 128;
  const int wr = w >> 1, wc = w & 1;

  // staging: wave w stages rows w*32..w*32+31 of A and B (2 GLL16 each, 1KB per call).
  // Within a GLL16 chunk of 16 rows: lane -> row = r0 + (lane>>2), dest slot = lane&3.
  // LDS[row][slot] holds global[row][slot ^ (row&3)]  (4-slot XOR, row&3 == (lane>>2)&3).
  const int sr = lane >> 2;
  const int sslot = (lane & 3) ^ (sr & 3);

  auto stage = [&](int kt, int b) {
    #pragma unroll
    for (int c = 0; c < 2; ++c) {
      int r0 = w * 32 + c * 16;
      int row = r0 + sr;
      const unsigned short* ga = A  + (size_t)(m0 + row) * D + kt * 32 + sslot * 8;
      const unsigned short* gb = Bm + (size_t)(n0 + row) * D + kt * 32 + sslot * 8;
      GLL16(ga, &Ash[b][r0 * 32]);
      GLL16(gb, &Bsh[b][r0 * 32]);
    }
  };

  f32x4 acc[4][4];
  #pragma unroll
  for (int m = 0; m < 4; ++m)
    #pragma unroll
    for (int n = 0; n < 4; ++n) acc[m][n] = (f32x4){0.f, 0.f, 0.f, 0.f};

  // prologue: 3 tiles in flight (12 GLL16/wave outstanding)
  stage(0, 0);
  stage(1, 1);
  stage(2, 2);

  const int rdsw = (lg ^ (lr & 3)) * 8;   // swizzled 16B-slot offset for fragment reads

  // one K-step: wait tile KT landed (vmcnt literal), barrier, refill, compute
#define GSTEP(KT, WN) { \
    asm volatile("s_waitcnt vmcnt(" #WN ")" ::: "memory"); \
    __builtin_amdgcn_s_barrier(); \
    if ((KT) + 3 < 16) stage((KT) + 3, ((KT) + 3) & 3); \
    const unsigned short* Ac = Ash[(KT) & 3]; \
    const unsigned short* Bc = Bsh[(KT) & 3]; \
    short8 af[4], bf[4]; \
    _Pragma("unroll") \
    for (int m = 0; m < 4; ++m) \
      af[m] = *(const short8*)&Ac[(wr * 64 + m * 16 + lr) * 32 + rdsw]; \
    _Pragma("unroll") \
    for (int n = 0; n < 4; ++n) \
      bf[n] = *(const short8*)&Bc[(wc * 64 + n * 16 + lr) * 32 + rdsw]; \
    __builtin_amdgcn_s_setprio(1); \
    _Pragma("unroll") \
    for (int m = 0; m < 4; ++m) \
      _Pragma("unroll") \
      for (int n = 0; n < 4; ++n) \
        acc[m][n] = __builtin_amdgcn_mfma_f32_16x16x32_bf16(af[m], bf[n], acc[m][n], 0, 0, 0); \
    __builtin_amdgcn_s_setprio(0); \
  }

  GSTEP(0, 8)  GSTEP(1, 8)  GSTEP(2, 8)  GSTEP(3, 8)
  GSTEP(4, 8)  GSTEP(5, 8)  GSTEP(6, 8)  GSTEP(7, 8)
  GSTEP(8, 8)  GSTEP(9, 8)  GSTEP(10, 8) GSTEP(11, 8)
  GSTEP(12, 8) GSTEP(13, 8) GSTEP(14, 4) GSTEP(15, 0)
#undef GSTEP

  // ---- epilogue ----
  if (EPI == 1 && nb >= 8) {
    // Vt block: e = col-1024 fixed per lane; acc rows r=0..3 are contiguous keys
    #pragma unroll
    for (int m = 0; m < 4; ++m) {
      #pragma unroll
      for (int n = 0; n < 4; ++n) {
        int e = (n0 - 1024) + wc * 64 + n * 16 + lr;
        int grow = m0 + wr * 64 + m * 16 + lg * 4;
        int bc = grow >> 9, key = grow & 511;
        ushort4 pk;
        pk.x = f2bf(acc[m][n][0]); pk.y = f2bf(acc[m][n][1]);
        pk.z = f2bf(acc[m][n][2]); pk.w = f2bf(acc[m][n][3]);
        *(ushort4*)&O2[(size_t)(bc * 512 + e) * 512 + key] = pk;
      }
    }
  } else {
    unsigned short* Od = O0;
    int cshift = 0;
    if (EPI == 1 && nb >= 4) { Od = O1; cshift = 512; }
    #pragma unroll
    for (int m = 0; m < 4; ++m) {
      #pragma unroll
      for (int n = 0; n < 4; ++n) {
        int col = n0 + wc * 64 + n * 16 + lr - cshift;
        #pragma unroll
        for (int r = 0; r < 4; ++r) {
          int row = m0 + wr * 64 + m * 16 + lg * 4 + r;
          Od[(size_t)row * D + col] = f2bf(acc[m][n][r]);
        }
      }
    }
  }
}

// ---------------- K3: local attention with LDS-staged K/V tiles ----------------
// grid = 4096 = 64 chunks x 8 heads x 8 q-blocks; block = 256 (4 waves x 16 q-rows)
__global__ __launch_bounds__(256, 2) void k_attn(
    const unsigned short* __restrict__ Q, const unsigned short* __restrict__ K,
    const unsigned short* __restrict__ Vt, unsigned short* __restrict__ attn_out) {
  __shared__ char kv[2][16384];
  __shared__ char plds[4][4096];
  int lane = threadIdx.x & 63, w = threadIdx.x >> 6;
  int lr = lane & 15, lg = lane >> 4;
  int work = ((blockIdx.x & 7) << 9) + (blockIdx.x >> 3);
  int qb = work & 7, h = (work >> 3) & 7, bc = work >> 6;
  int qrow0 = bc * 512 + qb * 64 + w * 16;
  const int kvrow0 = bc * 512;
  const int vrow0  = bc * 512 + h * 64;

  const unsigned short* qp = Q + (size_t)(qrow0 + lr) * D + h * 64 + lg * 8;
  short8 aq0 = *(const short8*)(qp);
  short8 aq1 = *(const short8*)(qp + 32);

  auto stageK = [&](int kt, char* buf) {
    #pragma unroll
    for (int c = 0; c < 4; ++c) {
      int r0 = w * 32 + c * 8;
      int row = r0 + (lane >> 3);
      int ecol = ((lane & 7) ^ (lane >> 3)) * 8;
      const unsigned short* src = K + (size_t)(kvrow0 + kt * 128 + row) * D + h * 64 + ecol;
      GLL16(src, buf + r0 * 128);
    }
  };
  auto stageV = [&](int kt, char* buf) {
    #pragma unroll
    for (int c = 0; c < 4; ++c) {
      int r0 = w * 16 + c * 4;
      int row = r0 + (lane >> 4);
      int cb = ((lane & 15) * 16) ^ ((row & 7) << 4);
      const unsigned short* src = Vt + (size_t)(vrow0 + row) * D + kt * 128 + (cb >> 1);
      GLL16(src, buf + r0 * 256);
    }
  };

  f32x4 acc[32];
  #pragma unroll
  for (int i = 0; i < 32; ++i) acc[i] = (f32x4){0.f, 0.f, 0.f, 0.f};

  stageK(0, kv[0]);
  __syncthreads();
  #pragma unroll
  for (int kt = 0; kt < 4; ++kt) {
    if (kt < 3) stageK(kt + 1, kv[(kt + 1) & 1]);
    const char* kb = kv[kt & 1];
    #pragma unroll
    for (int nt = 0; nt < 8; ++nt) {
      int row = nt * 16 + lr;
      int rb = row * 128;
      int s = (lr & 7) << 4;
      short8 b0 = *(const short8*)(kb + ((rb + lg * 16) ^ s));
      short8 b1 = *(const short8*)(kb + ((rb + 64 + lg * 16) ^ s));
      acc[kt * 8 + nt] = __builtin_amdgcn_mfma_f32_16x16x32_bf16(aq0, b0, acc[kt * 8 + nt], 0, 0, 0);
      acc[kt * 8 + nt] = __builtin_amdgcn_mfma_f32_16x16x32_bf16(aq1, b1, acc[kt * 8 + nt], 0, 0, 0);
    }
    __syncthreads();
  }

  stageV(0, kv[0]);

  float rmax[4] = {-1e30f, -1e30f, -1e30f, -1e30f};
  #pragma unroll
  for (int nt = 0; nt < 32; ++nt) {
    #pragma unroll
    for (int r = 0; r < 4; ++r) rmax[r] = fmaxf(rmax[r], acc[nt][r]);
  }
  #pragma unroll
  for (int r = 0; r < 4; ++r) {
    #pragma unroll
    for (int m = 1; m < 16; m <<= 1) rmax[r] = fmaxf(rmax[r], __shfl_xor(rmax[r], m));
  }
  const float scale = 0.125f;   // 1/sqrt(64)
  float rsum[4] = {0.f, 0.f, 0.f, 0.f};
  #pragma unroll
  for (int nt = 0; nt < 32; ++nt) {
    #pragma unroll
    for (int r = 0; r < 4; ++r) {
      float p = __expf((acc[nt][r] - rmax[r]) * scale);
      acc[nt][r] = p; rsum[r] += p;
    }
  }
  #pragma unroll
  for (int r = 0; r < 4; ++r) {
    #pragma unroll
    for (int m = 1; m < 16; m <<= 1) rsum[r] += __shfl_xor(rsum[r], m);
  }
  __syncthreads();

  char* pb = plds[w];
  f32x4 oacc[4];
  #pragma unroll
  for (int j = 0; j < 4; ++j) oacc[j] = (f32x4){0.f, 0.f, 0.f, 0.f};
  #pragma unroll
  for (int kt = 0; kt < 4; ++kt) {
    if (kt < 3) stageV(kt + 1, kv[(kt + 1) & 1]);
    #pragma unroll
    for (int nt = 0; nt < 8; ++nt) {
      #pragma unroll
      for (int r = 0; r < 4; ++r) {
        int prow = lg * 4 + r, pcol = nt * 16 + lr;
        int byt = (prow * 256 + pcol * 2) ^ ((prow & 7) << 4);
        *(unsigned short*)(pb + byt) = f2bf(acc[kt * 8 + nt][r]);
      }
    }
    const char* vb = kv[kt & 1];
    #pragma unroll
    for (int kk = 0; kk < 4; ++kk) {
      short8 a = *(const short8*)(pb + ((lr * 256 + kk * 64 + lg * 16) ^ ((lr & 7) << 4)));
      #pragma unroll
      for (int j = 0; j < 4; ++j) {
        int row = j * 16 + lr;
        short8 b = *(const short8*)(vb + ((row * 256 + kk * 64 + lg * 16) ^ ((row & 7) << 4)));
        oacc[j] = __builtin_amdgcn_mfma_f32_16x16x32_bf16(a, b, oacc[j], 0, 0, 0);
      }
    }
    __syncthreads();
  }

  float inv[4];
  #pragma unroll
  for (int r = 0; r < 4; ++r) inv[r] = 1.f / rsum[r];
  #pragma unroll
  for (int j = 0; j < 4; ++j) {
    int col = h * 64 + j * 16 + lr;
    #pragma unroll
    for (int r = 0; r < 4; ++r) {
      int row = qrow0 + lg * 4 + r;
      attn_out[(size_t)row * D + col] = f2bf(oacc[j][r] * inv[r]);
    }
  }
}

// ---------------- K4b: per-chunk mean -> summaries fp32 [64][512] ----------------
__global__ __launch_bounds__(256) void k_mean(const unsigned short* __restrict__ lout,
                                              float* __restrict__ summ) {
  int bc = blockIdx.x;
  int col = blockIdx.y * 256 + threadIdx.x;
  const unsigned short* p = lout + (size_t)bc * 512 * 512 + col;
  float s = 0.f;
  #pragma unroll 8
  for (int r = 0; r < 512; ++r) s += bf2f(p[(size_t)r * 512]);
  summ[bc * 512 + col] = s * (1.f / 512.f);
}

// ---------------- K5a: sg = summaries @ Wg.T (fp32, tiny) ----------------
__global__ __launch_bounds__(256) void k_sg(const float* __restrict__ summ,
                                            const float* __restrict__ Wg,
                                            float* __restrict__ sg) {
  __shared__ float srow[512];
  int m = blockIdx.x >> 1, half = blockIdx.x & 1;
  for (int i = threadIdx.x; i < 512; i += 256) srow[i] = summ[m * 512 + i];
  __syncthreads();
  int n = half * 256 + threadIdx.x;
  const float* wr = Wg + (size_t)n * 512;
  float s = 0.f;
  #pragma unroll 8
  for (int kk = 0; kk < 512; ++kk) s += srow[kk] * wr[kk];
  sg[m * 512 + n] = s;
}

// ---------------- K5b: cross-chunk attention (fp32, tiny) ----------------
__global__ __launch_bounds__(256) void k_gattn(const float* __restrict__ sg,
                                               float* __restrict__ gctx) {
  __shared__ float qs[32][64];
  __shared__ float sc[32][32];
  int b = blockIdx.x >> 3, h = blockIdx.x & 7;
  int tid = threadIdx.x;
  for (int i = tid; i < 2048; i += 256) {
    int r = i >> 6, e = i & 63;
    qs[r][e] = sg[(size_t)(b * 32 + r) * 512 + h * 64 + e];
  }
  __syncthreads();
  for (int p = tid; p < 1024; p += 256) {
    int qi = p >> 5, ki = p & 31;
    float s = 0.f;
    #pragma unroll 8
    for (int e = 0; e < 64; ++e) s += qs[qi][e] * qs[ki][e];
    sc[qi][ki] = s * 0.125f;
  }
  __syncthreads();
  if (tid < 32) {
    float mx = -1e30f;
    for (int k2 = 0; k2 < 32; ++k2) mx = fmaxf(mx, sc[tid][k2]);
    float sm = 0.f;
    for (int k2 = 0; k2 < 32; ++k2) { float p = __expf(sc[tid][k2] - mx); sc[tid][k2] = p; sm += p; }
    float iv = 1.f / sm;
    for (int k2 = 0; k2 < 32; ++k2) sc[tid][k2] *= iv;
  }
  __syncthreads();
  for (int i = tid; i < 2048; i += 256) {
    int r = i >> 6, e = i & 63;
    float o = 0.f;
    #pragma unroll 8
    for (int k2 = 0; k2 < 32; ++k2) o += sc[r][k2] * qs[k2][e];
    gctx[(size_t)(b * 32 + r) * 512 + h * 64 + e] = o;
  }
}

// ---------------- K6: out = local_out + broadcast(gctx), fp32 output ----------------
__global__ __launch_bounds__(256) void k_final(const unsigned short* __restrict__ lout,
                                               const float* __restrict__ gctx,
                                               float* __restrict__ out) {
  size_t idx = (size_t)blockIdx.x * 256 + threadIdx.x;
  size_t i = idx * 4;
  int c = (int)(i & 511);
  int bcg = (int)(i >> 18);
  ushort4 lv = *(const ushort4*)(lout + i);
  float4 g = *(const float4*)(gctx + (size_t)bcg * 512 + c);
  float4 o;
  o.x = bf2f(lv.x) + g.x;
  o.y = bf2f(lv.y) + g.y;
  o.z = bf2f(lv.z) + g.z;
  o.w = bf2f(lv.w) + g.w;
  *(float4*)(out + i) = o;
}

extern "C" void kernel_launch(void* const* d_in, const int* in_sizes, int n_in,
                              void* d_out, int out_size, void* d_ws, size_t ws_size,
                              hipStream_t stream) {
  const float* x  = (const float*)d_in[0];
  const float* Wq = (const float*)d_in[1];
  const float* Wk = (const float*)d_in[2];
  const float* Wv = (const float*)d_in[3];
  const float* Wo = (const float*)d_in[4];
  const float* Wg = (const float*)d_in[5];
  float* out = (float*)d_out;

  char* ws = (char*)d_ws;
  unsigned short* xb   = (unsigned short*)(ws);                 // 32 MB  [A]
  unsigned short* q    = (unsigned short*)(ws + 33554432);      // 32 MB  [B]
  unsigned short* kb   = (unsigned short*)(ws + 67108864);      // 32 MB  [C]
  unsigned short* vt   = (unsigned short*)(ws + 100663296);     // 32 MB  [D]
  unsigned short* wqkv = (unsigned short*)(ws + 134217728);     // 1.5 MB
  unsigned short* wo_b = (unsigned short*)(ws + 135790592);     // 0.5 MB
  float* summ = (float*)(ws + 136314880);                       // 128 KB
  float* sgp  = (float*)(ws + 136445952);                       // 128 KB
  float* gctx = (float*)(ws + 136577024);                       // 128 KB
  unsigned short* attn_out = xb;   // region A reused (xb dead after k_qkv)
  unsigned short* local_bf = q;    // region B reused (q dead after k_attn)

  k_convert<<<17408, 256, 0, stream>>>(x, Wq, Wk, Wv, Wo, xb, wqkv, wo_b);
  k_gemm<12, 1><<<3072, 256, 0, stream>>>(xb, wqkv, q, kb, vt);
  k_attn<<<4096, 256, 0, stream>>>(q, kb, vt, attn_out);
  k_gemm<4, 0><<<1024, 256, 0, stream>>>(attn_out, wo_b, local_bf, nullptr, nullptr);
  k_mean<<<dim3(64, 2), 256, 0, stream>>>(local_bf, summ);
  k_sg<<<128, 256, 0, stream>>>(summ, Wg, sgp);
  k_gattn<<<16, 256, 0, stream>>>(sgp, gctx);
  k_final<<<16384, 256, 0, stream>>>(local_bf, gctx, out);
}

// Round 6
// 256.076 us; speedup vs baseline: 3.7204x; 1.1519x over previous
//
#include <hip/hip_runtime.h>

typedef __attribute__((ext_vector_type(8))) short short8;
typedef __attribute__((ext_vector_type(4))) float f32x4;
typedef __attribute__((ext_vector_type(16))) float f32x16;

#define DEV static __device__ __forceinline__

DEV float bf2f(unsigned short u) {
  union { unsigned int u32; float f; } v; v.u32 = ((unsigned int)u) << 16; return v.f;
}
DEV unsigned short f2bf(float f) {
  union { float f; unsigned int u; } v; v.f = f;
  unsigned int r = v.u + 0x7fffu + ((v.u >> 16) & 1u);
  return (unsigned short)(r >> 16);
}
DEV unsigned cvtpk(float lo, float hi) {
  unsigned r;
  asm("v_cvt_pk_bf16_f32 %0, %1, %2" : "=v"(r) : "v"(lo), "v"(hi));
  return r;
}
DEV void plswap(unsigned &a, unsigned &b) {
  asm("v_permlane32_swap_b32 %0, %1" : "+v"(a), "+v"(b));
}
DEV short8 mk8(unsigned a, unsigned b, unsigned c, unsigned d) {
  union { unsigned u[4]; short8 v; } x;
  x.u[0] = a; x.u[1] = b; x.u[2] = c; x.u[3] = d; return x.v;
}

// async global->LDS, 16B per lane; LDS dest is wave-uniform base + lane*16
#define GLL16(g, l) __builtin_amdgcn_global_load_lds( \
    (const __attribute__((address_space(1))) void*)(g), \
    (__attribute__((address_space(3))) void*)(l), 16, 0, 0)

constexpr int D  = 512;
constexpr int BT = 32768;   // B*T rows

// ---------------- K1: fp32 -> bf16 conversion (x, Wq|Wk|Wv concat, Wo) ----------------
__global__ __launch_bounds__(256) void k_convert(
    const float* __restrict__ x, const float* __restrict__ Wq, const float* __restrict__ Wk,
    const float* __restrict__ Wv, const float* __restrict__ Wo,
    unsigned short* __restrict__ xb, unsigned short* __restrict__ wqkv,
    unsigned short* __restrict__ wo_b) {
  int idx = blockIdx.x * 256 + threadIdx.x;
  const int NX4 = (BT * D) / 4;      // 4,194,304
  const float* src; unsigned short* dst; size_t i4;
  if (idx < NX4) {
    src = x; dst = xb; i4 = (size_t)idx * 4;
  } else {
    int t = idx - NX4;
    int w = t >> 16;                 // NW4 = 512*512/4 = 65536
    int within = t & 65535;
    src = (w == 0) ? Wq : (w == 1) ? Wk : (w == 2) ? Wv : Wo;
    dst = (w < 3) ? (wqkv + (size_t)w * D * D) : wo_b;
    i4 = (size_t)within * 4;
  }
  float4 v = *(const float4*)(src + i4);
  ushort4 o; o.x = f2bf(v.x); o.y = f2bf(v.y); o.z = f2bf(v.z); o.w = f2bf(v.w);
  *(ushort4*)(dst + i4) = o;
}

// ---------------- deep-pipelined GEMM: C[M,N] = A[M,512] x B[N,512]^T ----------------
// 128x128 tile, BK=32, 4 waves (2x2), FOUR LDS buffers, prefetch depth 3,
// counted vmcnt(8) in steady state (T4: never drain to 0 in the main loop).
template<int NBLK, int EPI>
__global__ __launch_bounds__(256) void k_gemm(
    const unsigned short* __restrict__ A, const unsigned short* __restrict__ Bm,
    unsigned short* __restrict__ O0, unsigned short* __restrict__ O1,
    unsigned short* __restrict__ O2) {
  __shared__ unsigned short Ash[4][128 * 32];   // 32 KB
  __shared__ unsigned short Bsh[4][128 * 32];   // 32 KB
  const int tid = threadIdx.x;
  const int lane = tid & 63, w = tid >> 6;
  const int lr = lane & 15, lg = lane >> 4;
  const int cpx = gridDim.x >> 3;
  const int bid = blockIdx.x;
  const int work = (bid & 7) * cpx + (bid >> 3);
  const int nb = work % NBLK, mb = work / NBLK;
  const int m0 = mb * 128, n0 = nb * 128;
  const int wr = w >> 1, wc = w & 1;

  const int sr = lane >> 2;
  const int sslot = (lane & 3) ^ (sr & 3);

  auto stage = [&](int kt, int b) {
    #pragma unroll
    for (int c = 0; c < 2; ++c) {
      int r0 = w * 32 + c * 16;
      int row = r0 + sr;
      const unsigned short* ga = A  + (size_t)(m0 + row) * D + kt * 32 + sslot * 8;
      const unsigned short* gb = Bm + (size_t)(n0 + row) * D + kt * 32 + sslot * 8;
      GLL16(ga, &Ash[b][r0 * 32]);
      GLL16(gb, &Bsh[b][r0 * 32]);
    }
  };

  f32x4 acc[4][4];
  #pragma unroll
  for (int m = 0; m < 4; ++m)
    #pragma unroll
    for (int n = 0; n < 4; ++n) acc[m][n] = (f32x4){0.f, 0.f, 0.f, 0.f};

  stage(0, 0);
  stage(1, 1);
  stage(2, 2);

  const int rdsw = (lg ^ (lr & 3)) * 8;

#define GSTEP(KT, WN) { \
    asm volatile("s_waitcnt vmcnt(" #WN ")" ::: "memory"); \
    __builtin_amdgcn_s_barrier(); \
    if ((KT) + 3 < 16) stage((KT) + 3, ((KT) + 3) & 3); \
    const unsigned short* Ac = Ash[(KT) & 3]; \
    const unsigned short* Bc = Bsh[(KT) & 3]; \
    short8 af[4], bf[4]; \
    _Pragma("unroll") \
    for (int m = 0; m < 4; ++m) \
      af[m] = *(const short8*)&Ac[(wr * 64 + m * 16 + lr) * 32 + rdsw]; \
    _Pragma("unroll") \
    for (int n = 0; n < 4; ++n) \
      bf[n] = *(const short8*)&Bc[(wc * 64 + n * 16 + lr) * 32 + rdsw]; \
    __builtin_amdgcn_s_setprio(1); \
    _Pragma("unroll") \
    for (int m = 0; m < 4; ++m) \
      _Pragma("unroll") \
      for (int n = 0; n < 4; ++n) \
        acc[m][n] = __builtin_amdgcn_mfma_f32_16x16x32_bf16(af[m], bf[n], acc[m][n], 0, 0, 0); \
    __builtin_amdgcn_s_setprio(0); \
  }

  GSTEP(0, 8)  GSTEP(1, 8)  GSTEP(2, 8)  GSTEP(3, 8)
  GSTEP(4, 8)  GSTEP(5, 8)  GSTEP(6, 8)  GSTEP(7, 8)
  GSTEP(8, 8)  GSTEP(9, 8)  GSTEP(10, 8) GSTEP(11, 8)
  GSTEP(12, 8) GSTEP(13, 8) GSTEP(14, 4) GSTEP(15, 0)
#undef GSTEP

  if (EPI == 1 && nb >= 8) {
    #pragma unroll
    for (int m = 0; m < 4; ++m) {
      #pragma unroll
      for (int n = 0; n < 4; ++n) {
        int e = (n0 - 1024) + wc * 64 + n * 16 + lr;
        int grow = m0 + wr * 64 + m * 16 + lg * 4;
        int bc = grow >> 9, key = grow & 511;
        ushort4 pk;
        pk.x = f2bf(acc[m][n][0]); pk.y = f2bf(acc[m][n][1]);
        pk.z = f2bf(acc[m][n][2]); pk.w = f2bf(acc[m][n][3]);
        *(ushort4*)&O2[(size_t)(bc * 512 + e) * 512 + key] = pk;
      }
    }
  } else {
    unsigned short* Od = O0;
    int cshift = 0;
    if (EPI == 1 && nb >= 4) { Od = O1; cshift = 512; }
    #pragma unroll
    for (int m = 0; m < 4; ++m) {
      #pragma unroll
      for (int n = 0; n < 4; ++n) {
        int col = n0 + wc * 64 + n * 16 + lr - cshift;
        #pragma unroll
        for (int r = 0; r < 4; ++r) {
          int row = m0 + wr * 64 + m * 16 + lg * 4 + r;
          Od[(size_t)row * D + col] = f2bf(acc[m][n][r]);
        }
      }
    }
  }
}

// ---------------- K3: flash-style local attention, swapped 32x32 MFMA ----------------
// grid = 1024 = 64 chunks x 8 heads x 2 q-halves; block = 512 (8 waves x 32 q-rows).
// Online softmax in-register (each lane owns q-row = lane&31); P via cvt_pk+permlane32_swap
// (T12) straight into PV fragments — P never touches LDS. K/V tiles (64 keys) staged with
// global_load_lds, 3 buffers, depth-2 prefetch, counted vmcnt(2), 1 barrier/tile.
__global__ __launch_bounds__(512, 4) void k_attn(
    const unsigned short* __restrict__ Q, const unsigned short* __restrict__ K,
    const unsigned short* __restrict__ Vt, unsigned short* __restrict__ attn_out) {
  __shared__ char lds[3][16384];   // buf: [0,8K) K-tile [64keys][64d], [8K,16K) V-tile [64e][64k]
  const int tid = threadIdx.x;
  const int lane = tid & 63, w = tid >> 6;
  const int l31 = lane & 31, hl = lane >> 5;
  int work = ((blockIdx.x & 7) << 7) + (blockIdx.x >> 3);   // XCD-chunked swizzle (1024%8==0)
  int qh = work & 1, h = (work >> 1) & 7, bc = work >> 4;
  int qbase = bc * 512 + qh * 256 + w * 32;

  // Q B-frags: B[q=l31][k = ks*16 + hl*8 + j]
  short8 qf[4];
  {
    const unsigned short* qp = Q + (size_t)(qbase + l31) * D + h * 64 + hl * 8;
    #pragma unroll
    for (int ks = 0; ks < 4; ++ks) qf[ks] = *(const short8*)(qp + ks * 16);
  }

  // staging: 512 lanes x 16B = 8KB per GLL; LDS[row][slot] = G[row][slot ^ (row&7)]
  const int srow  = w * 8 + (lane >> 3);               // 0..63
  const int sslot = (lane & 7) ^ ((lane >> 3) & 7);
  const unsigned short* gK = K  + (size_t)(bc * 512 + srow) * D + h * 64 + sslot * 8;
  const unsigned short* gV = Vt + (size_t)(bc * 512 + h * 64 + srow) * D + sslot * 8;
  auto STAGE = [&](int T, int B) {
    GLL16(gK + (size_t)(T) * 64 * D, &lds[B][w * 1024]);
    GLL16(gV + (T) * 64,             &lds[B][8192 + w * 1024]);
  };

  f32x16 oA, oB;
  #pragma unroll
  for (int i = 0; i < 16; ++i) { oA[i] = 0.f; oB[i] = 0.f; }
  float mrun = -3e38f, lrun = 0.f;
  const float scale = 0.125f;   // 1/sqrt(64)
  const int x7 = l31 & 7;       // row&7 for all our tile reads

  STAGE(0, 0);
  STAGE(1, 1);

  #pragma unroll
  for (int t = 0; t < 8; ++t) {
    if (t == 0 || t == 7) asm volatile("s_waitcnt vmcnt(0)" ::: "memory");
    else                  asm volatile("s_waitcnt vmcnt(2)" ::: "memory");
    __builtin_amdgcn_s_barrier();
    if (t < 6) STAGE(t + 2, (t + 2) % 3);
    const char* kb = lds[t % 3];
    const char* vb = lds[t % 3] + 8192;

    // ---- QK^T swapped: S^T[key][q] = mfma(A=K, B=Q) ----
    f32x16 sA, sB;
    #pragma unroll
    for (int i = 0; i < 16; ++i) { sA[i] = 0.f; sB[i] = 0.f; }
    #pragma unroll
    for (int ks = 0; ks < 4; ++ks) {
      int sl = ((ks * 2 + hl) ^ x7) * 16;
      short8 kf0 = *(const short8*)(kb + l31 * 128 + sl);
      short8 kf1 = *(const short8*)(kb + (32 + l31) * 128 + sl);
      sA = __builtin_amdgcn_mfma_f32_32x32x16_bf16(kf0, qf[ks], sA, 0, 0, 0);
      sB = __builtin_amdgcn_mfma_f32_32x32x16_bf16(kf1, qf[ks], sB, 0, 0, 0);
    }

    // ---- online softmax (lane owns q = l31; partner lane^32 holds other key-half) ----
    float pm = sA[0];
    #pragma unroll
    for (int i = 1; i < 16; ++i) pm = fmaxf(pm, sA[i]);
    #pragma unroll
    for (int i = 0; i < 16; ++i) pm = fmaxf(pm, sB[i]);
    pm = fmaxf(pm, __shfl_xor(pm, 32));
    float mnew = fmaxf(mrun, pm);
    float alpha = __expf((mrun - mnew) * scale);
    float ls = 0.f;
    #pragma unroll
    for (int i = 0; i < 16; ++i) { float p = __expf((sA[i] - mnew) * scale); sA[i] = p; ls += p; }
    #pragma unroll
    for (int i = 0; i < 16; ++i) { float p = __expf((sB[i] - mnew) * scale); sB[i] = p; ls += p; }
    ls += __shfl_xor(ls, 32);
    lrun = lrun * alpha + ls;
    mrun = mnew;
    #pragma unroll
    for (int i = 0; i < 16; ++i) { oA[i] *= alpha; oB[i] *= alpha; }

    // ---- P repack to PV fragments: cvt_pk + permlane32_swap (T12) ----
    unsigned dA[8], dB[8];
    #pragma unroll
    for (int i = 0; i < 8; ++i) {
      dA[i] = cvtpk(sA[2 * i], sA[2 * i + 1]);
      dB[i] = cvtpk(sB[2 * i], sB[2 * i + 1]);
    }
    plswap(dA[0], dA[2]); plswap(dA[1], dA[3]);
    plswap(dA[4], dA[6]); plswap(dA[5], dA[7]);
    plswap(dB[0], dB[2]); plswap(dB[1], dB[3]);
    plswap(dB[4], dB[6]); plswap(dB[5], dB[7]);
    short8 pf[4] = { mk8(dA[0], dA[1], dA[2], dA[3]), mk8(dA[4], dA[5], dA[6], dA[7]),
                     mk8(dB[0], dB[1], dB[2], dB[3]), mk8(dB[4], dB[5], dB[6], dB[7]) };

    // ---- PV swapped: O^T[e][q] += mfma(A=V, B=P) ----
    #pragma unroll
    for (int k4 = 0; k4 < 4; ++k4) {
      int sl = ((k4 * 2 + hl) ^ x7) * 16;
      short8 vf0 = *(const short8*)(vb + l31 * 128 + sl);
      short8 vf1 = *(const short8*)(vb + (32 + l31) * 128 + sl);
      oA = __builtin_amdgcn_mfma_f32_32x32x16_bf16(vf0, pf[k4], oA, 0, 0, 0);
      oB = __builtin_amdgcn_mfma_f32_32x32x16_bf16(vf1, pf[k4], oB, 0, 0, 0);
    }
  }

  // ---- epilogue: normalize, transpose O^T -> O via per-wave LDS region ----
  __syncthreads();                      // all waves done reading KV bufs
  float inv = 1.f / lrun;
  char* tr = &lds[0][0] + w * 4096;     // [32 q][64 e] bf16, XOR-swizzled rows
  #pragma unroll
  for (int r = 0; r < 16; ++r) {
    int e0 = (r & 3) + 8 * (r >> 2) + 4 * hl;
    *(unsigned short*)(tr + ((l31 * 128 + e0 * 2) ^ (x7 << 4)))        = f2bf(oA[r] * inv);
    *(unsigned short*)(tr + ((l31 * 128 + (32 + e0) * 2) ^ (x7 << 4))) = f2bf(oB[r] * inv);
  }
  // same-wave readback (compiler orders via lgkmcnt), coalesced 16B global stores
  unsigned short* op = attn_out + (size_t)(qbase + l31) * D + h * 64 + hl * 32;
  #pragma unroll
  for (int s = 0; s < 4; ++s) {
    int slot = (hl * 4 + s) ^ x7;
    short8 v = *(const short8*)(tr + l31 * 128 + slot * 16);
    *(short8*)(op + s * 8) = v;
  }
}

// ---------------- K4b: per-chunk mean -> summaries fp32 [64][512] ----------------
__global__ __launch_bounds__(256) void k_mean(const unsigned short* __restrict__ lout,
                                              float* __restrict__ summ) {
  int bc = blockIdx.x;
  int col = blockIdx.y * 256 + threadIdx.x;
  const unsigned short* p = lout + (size_t)bc * 512 * 512 + col;
  float s = 0.f;
  #pragma unroll 8
  for (int r = 0; r < 512; ++r) s += bf2f(p[(size_t)r * 512]);
  summ[bc * 512 + col] = s * (1.f / 512.f);
}

// ---------------- K5a: sg = summaries @ Wg.T (fp32, tiny) ----------------
__global__ __launch_bounds__(256) void k_sg(const float* __restrict__ summ,
                                            const float* __restrict__ Wg,
                                            float* __restrict__ sg) {
  __shared__ float srow[512];
  int m = blockIdx.x >> 1, half = blockIdx.x & 1;
  for (int i = threadIdx.x; i < 512; i += 256) srow[i] = summ[m * 512 + i];
  __syncthreads();
  int n = half * 256 + threadIdx.x;
  const float* wr = Wg + (size_t)n * 512;
  float s = 0.f;
  #pragma unroll 8
  for (int kk = 0; kk < 512; ++kk) s += srow[kk] * wr[kk];
  sg[m * 512 + n] = s;
}

// ---------------- K5b: cross-chunk attention (fp32, tiny) ----------------
__global__ __launch_bounds__(256) void k_gattn(const float* __restrict__ sg,
                                               float* __restrict__ gctx) {
  __shared__ float qs[32][64];
  __shared__ float sc[32][32];
  int b = blockIdx.x >> 3, h = blockIdx.x & 7;
  int tid = threadIdx.x;
  for (int i = tid; i < 2048; i += 256) {
    int r = i >> 6, e = i & 63;
    qs[r][e] = sg[(size_t)(b * 32 + r) * 512 + h * 64 + e];
  }
  __syncthreads();
  for (int p = tid; p < 1024; p += 256) {
    int qi = p >> 5, ki = p & 31;
    float s = 0.f;
    #pragma unroll 8
    for (int e = 0; e < 64; ++e) s += qs[qi][e] * qs[ki][e];
    sc[qi][ki] = s * 0.125f;
  }
  __syncthreads();
  if (tid < 32) {
    float mx = -1e30f;
    for (int k2 = 0; k2 < 32; ++k2) mx = fmaxf(mx, sc[tid][k2]);
    float sm = 0.f;
    for (int k2 = 0; k2 < 32; ++k2) { float p = __expf(sc[tid][k2] - mx); sc[tid][k2] = p; sm += p; }
    float iv = 1.f / sm;
    for (int k2 = 0; k2 < 32; ++k2) sc[tid][k2] *= iv;
  }
  __syncthreads();
  for (int i = tid; i < 2048; i += 256) {
    int r = i >> 6, e = i & 63;
    float o = 0.f;
    #pragma unroll 8
    for (int k2 = 0; k2 < 32; ++k2) o += sc[r][k2] * qs[k2][e];
    gctx[(size_t)(b * 32 + r) * 512 + h * 64 + e] = o;
  }
}

// ---------------- K6: out = local_out + broadcast(gctx), fp32 output ----------------
__global__ __launch_bounds__(256) void k_final(const unsigned short* __restrict__ lout,
                                               const float* __restrict__ gctx,
                                               float* __restrict__ out) {
  size_t idx = (size_t)blockIdx.x * 256 + threadIdx.x;
  size_t i = idx * 4;
  int c = (int)(i & 511);
  int bcg = (int)(i >> 18);
  ushort4 lv = *(const ushort4*)(lout + i);
  float4 g = *(const float4*)(gctx + (size_t)bcg * 512 + c);
  float4 o;
  o.x = bf2f(lv.x) + g.x;
  o.y = bf2f(lv.y) + g.y;
  o.z = bf2f(lv.z) + g.z;
  o.w = bf2f(lv.w) + g.w;
  *(float4*)(out + i) = o;
}

extern "C" void kernel_launch(void* const* d_in, const int* in_sizes, int n_in,
                              void* d_out, int out_size, void* d_ws, size_t ws_size,
                              hipStream_t stream) {
  const float* x  = (const float*)d_in[0];
  const float* Wq = (const float*)d_in[1];
  const float* Wk = (const float*)d_in[2];
  const float* Wv = (const float*)d_in[3];
  const float* Wo = (const float*)d_in[4];
  const float* Wg = (const float*)d_in[5];
  float* out = (float*)d_out;

  char* ws = (char*)d_ws;
  unsigned short* xb   = (unsigned short*)(ws);                 // 32 MB  [A]
  unsigned short* q    = (unsigned short*)(ws + 33554432);      // 32 MB  [B]
  unsigned short* kb   = (unsigned short*)(ws + 67108864);      // 32 MB  [C]
  unsigned short* vt   = (unsigned short*)(ws + 100663296);     // 32 MB  [D]
  unsigned short* wqkv = (unsigned short*)(ws + 134217728);     // 1.5 MB
  unsigned short* wo_b = (unsigned short*)(ws + 135790592);     // 0.5 MB
  float* summ = (float*)(ws + 136314880);                       // 128 KB
  float* sgp  = (float*)(ws + 136445952);                       // 128 KB
  float* gctx = (float*)(ws + 136577024);                       // 128 KB
  unsigned short* attn_out = xb;   // region A reused (xb dead after k_qkv)
  unsigned short* local_bf = q;    // region B reused (q dead after k_attn)

  k_convert<<<17408, 256, 0, stream>>>(x, Wq, Wk, Wv, Wo, xb, wqkv, wo_b);
  k_gemm<12, 1><<<3072, 256, 0, stream>>>(xb, wqkv, q, kb, vt);
  k_attn<<<1024, 512, 0, stream>>>(q, kb, vt, attn_out);
  k_gemm<4, 0><<<1024, 256, 0, stream>>>(attn_out, wo_b, local_bf, nullptr, nullptr);
  k_mean<<<dim3(64, 2), 256, 0, stream>>>(local_bf, summ);
  k_sg<<<128, 256, 0, stream>>>(summ, Wg, sgp);
  k_gattn<<<16, 256, 0, stream>>>(sgp, gctx);
  k_final<<<16384, 256, 0, stream>>>(local_bf, gctx, out);
}

// Round 7
// 235.282 us; speedup vs baseline: 4.0492x; 1.0884x over previous
//
#include <hip/hip_runtime.h>

typedef __attribute__((ext_vector_type(8))) short short8;
typedef __attribute__((ext_vector_type(4))) float f32x4;
typedef __attribute__((ext_vector_type(16))) float f32x16;

#define DEV static __device__ __forceinline__

DEV float bf2f(unsigned short u) {
  union { unsigned int u32; float f; } v; v.u32 = ((unsigned int)u) << 16; return v.f;
}
DEV unsigned short f2bf(float f) {
  union { float f; unsigned int u; } v; v.f = f;
  unsigned int r = v.u + 0x7fffu + ((v.u >> 16) & 1u);
  return (unsigned short)(r >> 16);
}
DEV unsigned cvtpk(float lo, float hi) {
  unsigned r;
  asm("v_cvt_pk_bf16_f32 %0, %1, %2" : "=v"(r) : "v"(lo), "v"(hi));
  return r;
}
DEV void plswap(unsigned &a, unsigned &b) {
  asm("v_permlane32_swap_b32 %0, %1" : "+v"(a), "+v"(b));
}
DEV short8 mk8(unsigned a, unsigned b, unsigned c, unsigned d) {
  union { unsigned u[4]; short8 v; } x;
  x.u[0] = a; x.u[1] = b; x.u[2] = c; x.u[3] = d; return x.v;
}

// async global->LDS, 16B per lane; LDS dest is wave-uniform base + lane*16
#define GLL16(g, l) __builtin_amdgcn_global_load_lds( \
    (const __attribute__((address_space(1))) void*)(g), \
    (__attribute__((address_space(3))) void*)(l), 16, 0, 0)

constexpr int D  = 512;
constexpr int BT = 32768;   // B*T rows

// ---------------- K1: fp32 -> bf16 conversion (x, Wq|Wk|Wv concat, Wo) ----------------
__global__ __launch_bounds__(256) void k_convert(
    const float* __restrict__ x, const float* __restrict__ Wq, const float* __restrict__ Wk,
    const float* __restrict__ Wv, const float* __restrict__ Wo,
    unsigned short* __restrict__ xb, unsigned short* __restrict__ wqkv,
    unsigned short* __restrict__ wo_b) {
  int idx = blockIdx.x * 256 + threadIdx.x;
  const int NX4 = (BT * D) / 4;      // 4,194,304
  const float* src; unsigned short* dst; size_t i4;
  if (idx < NX4) {
    src = x; dst = xb; i4 = (size_t)idx * 4;
  } else {
    int t = idx - NX4;
    int w = t >> 16;                 // NW4 = 512*512/4 = 65536
    int within = t & 65535;
    src = (w == 0) ? Wq : (w == 1) ? Wk : (w == 2) ? Wv : Wo;
    dst = (w < 3) ? (wqkv + (size_t)w * D * D) : wo_b;
    i4 = (size_t)within * 4;
  }
  float4 v = *(const float4*)(src + i4);
  ushort4 o; o.x = f2bf(v.x); o.y = f2bf(v.y); o.z = f2bf(v.z); o.w = f2bf(v.w);
  *(ushort4*)(dst + i4) = o;
}

// ---------------- GEMM v3: C[M,N] = A[M,512] x B[N,512]^T ----------------
// 128(M) x 256(N) tile, BK=32, 8 waves (2x4), 512 threads, THREE LDS buffers,
// prefetch depth 2, counted vmcnt(3) steady state (T4), conflict-free 4-slot XOR
// swizzle: LDS[row][slot] = G[row][slot ^ ((row>>1)&3)]  (read quad = (4*lr+slot)&7
// covers all 8 quads per 8-lane group -> 0 bank conflicts on ds_read_b128).
// EPI 0: C -> O0 row-major. EPI 1 (NBLK=6): nb 0-1 Q, 2-3 K, 4-5 Vt-scatter.
template<int NBLK, int EPI>
__global__ __launch_bounds__(512, 4) void k_gemm(
    const unsigned short* __restrict__ A, const unsigned short* __restrict__ Bm,
    unsigned short* __restrict__ O0, unsigned short* __restrict__ O1,
    unsigned short* __restrict__ O2) {
  __shared__ unsigned short Ash[3][128 * 32];   // 24 KB
  __shared__ unsigned short Bsh[3][256 * 32];   // 48 KB
  const int tid = threadIdx.x;
  const int lane = tid & 63, w = tid >> 6;      // 8 waves
  const int lr = lane & 15, lg = lane >> 4;
  // bijective XCD-chunked swizzle (gridDim %8 == 0 for all instantiations)
  const int cpx = gridDim.x >> 3;
  const int bid = blockIdx.x;
  const int work = (bid & 7) * cpx + (bid >> 3);
  const int nb = work % NBLK, mb = work / NBLK;
  const int m0 = mb * 128, n0 = nb * 256;
  const int wr = w >> 2, wc = w & 3;            // wave tile: 64 rows x 64 cols

  // staging: thread -> (row = base + lane>>2, slot = lane&3); source col pre-swizzled
  const int sr = lane >> 2;
  const int sg8 = ((lane & 3) ^ ((lane >> 3) & 3)) * 8;
  const unsigned short* gA  = A  + (size_t)(m0 + w * 16 + sr) * D + sg8;
  const unsigned short* gB0 = Bm + (size_t)(n0 + w * 16 + sr) * D + sg8;
  const unsigned short* gB1 = Bm + (size_t)(n0 + 128 + w * 16 + sr) * D + sg8;

  auto stage = [&](int kt, int b) {
    GLL16(gA  + kt * 32, &Ash[b][w * 512]);
    GLL16(gB0 + kt * 32, &Bsh[b][w * 512]);
    GLL16(gB1 + kt * 32, &Bsh[b][(128 + w * 16) * 32]);
  };

  f32x4 acc[4][4];
  #pragma unroll
  for (int m = 0; m < 4; ++m)
    #pragma unroll
    for (int n = 0; n < 4; ++n) acc[m][n] = (f32x4){0.f, 0.f, 0.f, 0.f};

  // prologue: 2 tiles in flight (6 GLL16/thread outstanding)
  stage(0, 0);
  stage(1, 1);

  const int rdsw = (lg ^ ((lr >> 1) & 3)) * 8;   // conflict-free read slot

#define GSTEP(KT, WN) { \
    asm volatile("s_waitcnt vmcnt(" #WN ")" ::: "memory"); \
    __builtin_amdgcn_s_barrier(); \
    if ((KT) + 2 < 16) stage((KT) + 2, ((KT) + 2) % 3); \
    const unsigned short* Ac = Ash[(KT) % 3]; \
    const unsigned short* Bc = Bsh[(KT) % 3]; \
    short8 af[4], bf[4]; \
    _Pragma("unroll") \
    for (int m = 0; m < 4; ++m) \
      af[m] = *(const short8*)&Ac[(wr * 64 + m * 16 + lr) * 32 + rdsw]; \
    _Pragma("unroll") \
    for (int n = 0; n < 4; ++n) \
      bf[n] = *(const short8*)&Bc[(wc * 64 + n * 16 + lr) * 32 + rdsw]; \
    __builtin_amdgcn_s_setprio(1); \
    _Pragma("unroll") \
    for (int m = 0; m < 4; ++m) \
      _Pragma("unroll") \
      for (int n = 0; n < 4; ++n) \
        acc[m][n] = __builtin_amdgcn_mfma_f32_16x16x32_bf16(af[m], bf[n], acc[m][n], 0, 0, 0); \
    __builtin_amdgcn_s_setprio(0); \
  }

  GSTEP(0, 3)  GSTEP(1, 3)  GSTEP(2, 3)  GSTEP(3, 3)
  GSTEP(4, 3)  GSTEP(5, 3)  GSTEP(6, 3)  GSTEP(7, 3)
  GSTEP(8, 3)  GSTEP(9, 3)  GSTEP(10, 3) GSTEP(11, 3)
  GSTEP(12, 3) GSTEP(13, 3) GSTEP(14, 3) GSTEP(15, 0)
#undef GSTEP

  // ---- epilogue ----
  if (EPI == 1 && nb >= 4) {
    // Vt scatter: e = col-1024 fixed per lane; acc rows r=0..3 are contiguous keys
    #pragma unroll
    for (int m = 0; m < 4; ++m) {
      #pragma unroll
      for (int n = 0; n < 4; ++n) {
        int e = (n0 - 1024) + wc * 64 + n * 16 + lr;
        int grow = m0 + wr * 64 + m * 16 + lg * 4;
        int bc = grow >> 9, key = grow & 511;
        ushort4 pk;
        pk.x = f2bf(acc[m][n][0]); pk.y = f2bf(acc[m][n][1]);
        pk.z = f2bf(acc[m][n][2]); pk.w = f2bf(acc[m][n][3]);
        *(ushort4*)&O2[(size_t)(bc * 512 + e) * 512 + key] = pk;
      }
    }
  } else {
    unsigned short* Od = O0;
    int cshift = 0;
    if (EPI == 1 && nb >= 2) { Od = O1; cshift = 512; }
    #pragma unroll
    for (int m = 0; m < 4; ++m) {
      #pragma unroll
      for (int n = 0; n < 4; ++n) {
        int col = n0 + wc * 64 + n * 16 + lr - cshift;
        #pragma unroll
        for (int r = 0; r < 4; ++r) {
          int row = m0 + wr * 64 + m * 16 + lg * 4 + r;
          Od[(size_t)row * D + col] = f2bf(acc[m][n][r]);
        }
      }
    }
  }
}

// ---------------- K3: flash-style local attention, swapped 32x32 MFMA ----------------
// grid = 1024 = 64 chunks x 8 heads x 2 q-halves; block = 512 (8 waves x 32 q-rows).
__global__ __launch_bounds__(512, 4) void k_attn(
    const unsigned short* __restrict__ Q, const unsigned short* __restrict__ K,
    const unsigned short* __restrict__ Vt, unsigned short* __restrict__ attn_out) {
  __shared__ char lds[3][16384];   // buf: [0,8K) K-tile [64keys][64d], [8K,16K) V-tile [64e][64k]
  const int tid = threadIdx.x;
  const int lane = tid & 63, w = tid >> 6;
  const int l31 = lane & 31, hl = lane >> 5;
  int work = ((blockIdx.x & 7) << 7) + (blockIdx.x >> 3);   // XCD-chunked swizzle (1024%8==0)
  int qh = work & 1, h = (work >> 1) & 7, bc = work >> 4;
  int qbase = bc * 512 + qh * 256 + w * 32;

  // Q B-frags: B[q=l31][k = ks*16 + hl*8 + j]
  short8 qf[4];
  {
    const unsigned short* qp = Q + (size_t)(qbase + l31) * D + h * 64 + hl * 8;
    #pragma unroll
    for (int ks = 0; ks < 4; ++ks) qf[ks] = *(const short8*)(qp + ks * 16);
  }

  // staging: 512 lanes x 16B = 8KB per GLL; LDS[row][slot] = G[row][slot ^ (row&7)]
  const int srow  = w * 8 + (lane >> 3);               // 0..63
  const int sslot = (lane & 7) ^ ((lane >> 3) & 7);
  const unsigned short* gK = K  + (size_t)(bc * 512 + srow) * D + h * 64 + sslot * 8;
  const unsigned short* gV = Vt + (size_t)(bc * 512 + h * 64 + srow) * D + sslot * 8;
  auto STAGE = [&](int T, int B) {
    GLL16(gK + (size_t)(T) * 64 * D, &lds[B][w * 1024]);
    GLL16(gV + (T) * 64,             &lds[B][8192 + w * 1024]);
  };

  f32x16 oA, oB;
  #pragma unroll
  for (int i = 0; i < 16; ++i) { oA[i] = 0.f; oB[i] = 0.f; }
  float mrun = -3e38f, lrun = 0.f;
  const float scale = 0.125f;   // 1/sqrt(64)
  const int x7 = l31 & 7;       // row&7 for all our tile reads

  STAGE(0, 0);
  STAGE(1, 1);

  #pragma unroll
  for (int t = 0; t < 8; ++t) {
    if (t == 0 || t == 7) asm volatile("s_waitcnt vmcnt(0)" ::: "memory");
    else                  asm volatile("s_waitcnt vmcnt(2)" ::: "memory");
    __builtin_amdgcn_s_barrier();
    if (t < 6) STAGE(t + 2, (t + 2) % 3);
    const char* kb = lds[t % 3];
    const char* vb = lds[t % 3] + 8192;

    // ---- QK^T swapped: S^T[key][q] = mfma(A=K, B=Q) ----
    f32x16 sA, sB;
    #pragma unroll
    for (int i = 0; i < 16; ++i) { sA[i] = 0.f; sB[i] = 0.f; }
    #pragma unroll
    for (int ks = 0; ks < 4; ++ks) {
      int sl = ((ks * 2 + hl) ^ x7) * 16;
      short8 kf0 = *(const short8*)(kb + l31 * 128 + sl);
      short8 kf1 = *(const short8*)(kb + (32 + l31) * 128 + sl);
      sA = __builtin_amdgcn_mfma_f32_32x32x16_bf16(kf0, qf[ks], sA, 0, 0, 0);
      sB = __builtin_amdgcn_mfma_f32_32x32x16_bf16(kf1, qf[ks], sB, 0, 0, 0);
    }

    // ---- online softmax (lane owns q = l31; partner lane^32 holds other key-half) ----
    float pm = sA[0];
    #pragma unroll
    for (int i = 1; i < 16; ++i) pm = fmaxf(pm, sA[i]);
    #pragma unroll
    for (int i = 0; i < 16; ++i) pm = fmaxf(pm, sB[i]);
    pm = fmaxf(pm, __shfl_xor(pm, 32));
    float mnew = fmaxf(mrun, pm);
    float alpha = __expf((mrun - mnew) * scale);
    float ls = 0.f;
    #pragma unroll
    for (int i = 0; i < 16; ++i) { float p = __expf((sA[i] - mnew) * scale); sA[i] = p; ls += p; }
    #pragma unroll
    for (int i = 0; i < 16; ++i) { float p = __expf((sB[i] - mnew) * scale); sB[i] = p; ls += p; }
    ls += __shfl_xor(ls, 32);
    lrun = lrun * alpha + ls;
    mrun = mnew;
    #pragma unroll
    for (int i = 0; i < 16; ++i) { oA[i] *= alpha; oB[i] *= alpha; }

    // ---- P repack to PV fragments: cvt_pk + permlane32_swap (T12) ----
    unsigned dA[8], dB[8];
    #pragma unroll
    for (int i = 0; i < 8; ++i) {
      dA[i] = cvtpk(sA[2 * i], sA[2 * i + 1]);
      dB[i] = cvtpk(sB[2 * i], sB[2 * i + 1]);
    }
    plswap(dA[0], dA[2]); plswap(dA[1], dA[3]);
    plswap(dA[4], dA[6]); plswap(dA[5], dA[7]);
    plswap(dB[0], dB[2]); plswap(dB[1], dB[3]);
    plswap(dB[4], dB[6]); plswap(dB[5], dB[7]);
    short8 pf[4] = { mk8(dA[0], dA[1], dA[2], dA[3]), mk8(dA[4], dA[5], dA[6], dA[7]),
                     mk8(dB[0], dB[1], dB[2], dB[3]), mk8(dB[4], dB[5], dB[6], dB[7]) };

    // ---- PV swapped: O^T[e][q] += mfma(A=V, B=P) ----
    #pragma unroll
    for (int k4 = 0; k4 < 4; ++k4) {
      int sl = ((k4 * 2 + hl) ^ x7) * 16;
      short8 vf0 = *(const short8*)(vb + l31 * 128 + sl);
      short8 vf1 = *(const short8*)(vb + (32 + l31) * 128 + sl);
      oA = __builtin_amdgcn_mfma_f32_32x32x16_bf16(vf0, pf[k4], oA, 0, 0, 0);
      oB = __builtin_amdgcn_mfma_f32_32x32x16_bf16(vf1, pf[k4], oB, 0, 0, 0);
    }
  }

  // ---- epilogue: normalize, transpose O^T -> O via per-wave LDS region ----
  __syncthreads();                      // all waves done reading KV bufs
  float inv = 1.f / lrun;
  char* tr = &lds[0][0] + w * 4096;     // [32 q][64 e] bf16, XOR-swizzled rows
  #pragma unroll
  for (int r = 0; r < 16; ++r) {
    int e0 = (r & 3) + 8 * (r >> 2) + 4 * hl;
    *(unsigned short*)(tr + ((l31 * 128 + e0 * 2) ^ (x7 << 4)))        = f2bf(oA[r] * inv);
    *(unsigned short*)(tr + ((l31 * 128 + (32 + e0) * 2) ^ (x7 << 4))) = f2bf(oB[r] * inv);
  }
  // same-wave readback (compiler orders via lgkmcnt), coalesced 16B global stores
  unsigned short* op = attn_out + (size_t)(qbase + l31) * D + h * 64 + hl * 32;
  #pragma unroll
  for (int s = 0; s < 4; ++s) {
    int slot = (hl * 4 + s) ^ x7;
    short8 v = *(const short8*)(tr + l31 * 128 + slot * 16);
    *(short8*)(op + s * 8) = v;
  }
}

// ---------------- K4b: per-chunk mean -> summaries fp32 [64][512] ----------------
__global__ __launch_bounds__(256) void k_mean(const unsigned short* __restrict__ lout,
                                              float* __restrict__ summ) {
  int bc = blockIdx.x;
  int col = blockIdx.y * 256 + threadIdx.x;
  const unsigned short* p = lout + (size_t)bc * 512 * 512 + col;
  float s = 0.f;
  #pragma unroll 8
  for (int r = 0; r < 512; ++r) s += bf2f(p[(size_t)r * 512]);
  summ[bc * 512 + col] = s * (1.f / 512.f);
}

// ---------------- K5a: sg = summaries @ Wg.T (fp32, tiny) ----------------
__global__ __launch_bounds__(256) void k_sg(const float* __restrict__ summ,
                                            const float* __restrict__ Wg,
                                            float* __restrict__ sg) {
  __shared__ float srow[512];
  int m = blockIdx.x >> 1, half = blockIdx.x & 1;
  for (int i = threadIdx.x; i < 512; i += 256) srow[i] = summ[m * 512 + i];
  __syncthreads();
  int n = half * 256 + threadIdx.x;
  const float* wr = Wg + (size_t)n * 512;
  float s = 0.f;
  #pragma unroll 8
  for (int kk = 0; kk < 512; ++kk) s += srow[kk] * wr[kk];
  sg[m * 512 + n] = s;
}

// ---------------- K5b: cross-chunk attention (fp32, tiny) ----------------
__global__ __launch_bounds__(256) void k_gattn(const float* __restrict__ sg,
                                               float* __restrict__ gctx) {
  __shared__ float qs[32][64];
  __shared__ float sc[32][32];
  int b = blockIdx.x >> 3, h = blockIdx.x & 7;
  int tid = threadIdx.x;
  for (int i = tid; i < 2048; i += 256) {
    int r = i >> 6, e = i & 63;
    qs[r][e] = sg[(size_t)(b * 32 + r) * 512 + h * 64 + e];
  }
  __syncthreads();
  for (int p = tid; p < 1024; p += 256) {
    int qi = p >> 5, ki = p & 31;
    float s = 0.f;
    #pragma unroll 8
    for (int e = 0; e < 64; ++e) s += qs[qi][e] * qs[ki][e];
    sc[qi][ki] = s * 0.125f;
  }
  __syncthreads();
  if (tid < 32) {
    float mx = -1e30f;
    for (int k2 = 0; k2 < 32; ++k2) mx = fmaxf(mx, sc[tid][k2]);
    float sm = 0.f;
    for (int k2 = 0; k2 < 32; ++k2) { float p = __expf(sc[tid][k2] - mx); sc[tid][k2] = p; sm += p; }
    float iv = 1.f / sm;
    for (int k2 = 0; k2 < 32; ++k2) sc[tid][k2] *= iv;
  }
  __syncthreads();
  for (int i = tid; i < 2048; i += 256) {
    int r = i >> 6, e = i & 63;
    float o = 0.f;
    #pragma unroll 8
    for (int k2 = 0; k2 < 32; ++k2) o += sc[r][k2] * qs[k2][e];
    gctx[(size_t)(b * 32 + r) * 512 + h * 64 + e] = o;
  }
}

// ---------------- K6: out = local_out + broadcast(gctx), fp32 output ----------------
__global__ __launch_bounds__(256) void k_final(const unsigned short* __restrict__ lout,
                                               const float* __restrict__ gctx,
                                               float* __restrict__ out) {
  size_t idx = (size_t)blockIdx.x * 256 + threadIdx.x;
  size_t i = idx * 4;
  int c = (int)(i & 511);
  int bcg = (int)(i >> 18);
  ushort4 lv = *(const ushort4*)(lout + i);
  float4 g = *(const float4*)(gctx + (size_t)bcg * 512 + c);
  float4 o;
  o.x = bf2f(lv.x) + g.x;
  o.y = bf2f(lv.y) + g.y;
  o.z = bf2f(lv.z) + g.z;
  o.w = bf2f(lv.w) + g.w;
  *(float4*)(out + i) = o;
}

extern "C" void kernel_launch(void* const* d_in, const int* in_sizes, int n_in,
                              void* d_out, int out_size, void* d_ws, size_t ws_size,
                              hipStream_t stream) {
  const float* x  = (const float*)d_in[0];
  const float* Wq = (const float*)d_in[1];
  const float* Wk = (const float*)d_in[2];
  const float* Wv = (const float*)d_in[3];
  const float* Wo = (const float*)d_in[4];
  const float* Wg = (const float*)d_in[5];
  float* out = (float*)d_out;

  char* ws = (char*)d_ws;
  unsigned short* xb   = (unsigned short*)(ws);                 // 32 MB  [A]
  unsigned short* q    = (unsigned short*)(ws + 33554432);      // 32 MB  [B]
  unsigned short* kb   = (unsigned short*)(ws + 67108864);      // 32 MB  [C]
  unsigned short* vt   = (unsigned short*)(ws + 100663296);     // 32 MB  [D]
  unsigned short* wqkv = (unsigned short*)(ws + 134217728);     // 1.5 MB
  unsigned short* wo_b = (unsigned short*)(ws + 135790592);     // 0.5 MB
  float* summ = (float*)(ws + 136314880);                       // 128 KB
  float* sgp  = (float*)(ws + 136445952);                       // 128 KB
  float* gctx = (float*)(ws + 136577024);                       // 128 KB
  unsigned short* attn_out = xb;   // region A reused (xb dead after k_qkv)
  unsigned short* local_bf = q;    // region B reused (q dead after k_attn)

  k_convert<<<17408, 256, 0, stream>>>(x, Wq, Wk, Wv, Wo, xb, wqkv, wo_b);
  // QKV: M=32768, N=1536 -> 256 x 6 = 1536 blocks, 512 threads
  k_gemm<6, 1><<<1536, 512, 0, stream>>>(xb, wqkv, q, kb, vt);
  k_attn<<<1024, 512, 0, stream>>>(q, kb, vt, attn_out);
  // Wo: M=32768, N=512 -> 256 x 2 = 512 blocks, 512 threads
  k_gemm<2, 0><<<512, 512, 0, stream>>>(attn_out, wo_b, local_bf, nullptr, nullptr);
  k_mean<<<dim3(64, 2), 256, 0, stream>>>(local_bf, summ);
  k_sg<<<128, 256, 0, stream>>>(summ, Wg, sgp);
  k_gattn<<<16, 256, 0, stream>>>(sgp, gctx);
  k_final<<<16384, 256, 0, stream>>>(local_bf, gctx, out);
}